// Round 1
// baseline (1846.614 us; speedup 1.0000x reference)
//
#include <hip/hip_runtime.h>
#include <math.h>

#define CCH    512
#define HWN    4096
#define BATCH  16
#define NPIX   65536
#define OC3    1536
#define DIMH   64
#define QSCALE 0.125f
#define LN_EPS 1e-5f

__device__ __forceinline__ float waveReduceSum(float v) {
#pragma unroll
    for (int off = 32; off; off >>= 1) v += __shfl_xor(v, off);
    return v;
}
__device__ __forceinline__ float waveReduceMax(float v) {
#pragma unroll
    for (int off = 32; off; off >>= 1) v = fmaxf(v, __shfl_xor(v, off));
    return v;
}

// ---------------------------------------------------------------------------
// A: wg[o,c] = w_qkv[o,c] * g_ln[c];  s[o] = sum_c wg[o,c]
__global__ __launch_bounds__(64) void prep_wg(const float* __restrict__ w_qkv,
                                              const float* __restrict__ g_ln,
                                              float* __restrict__ wg,
                                              float* __restrict__ s) {
    const int o = blockIdx.x;
    const int lane = threadIdx.x;
    float sum = 0.f;
#pragma unroll
    for (int j = 0; j < 8; ++j) {
        const int c = lane + j * 64;
        const float w = w_qkv[(size_t)o * CCH + c] * g_ln[c];
        wg[(size_t)o * CCH + c] = w;
        sum += w;
    }
    sum = waveReduceSum(sum);
    if (lane == 0) s[o] = sum;
}

// ---------------------------------------------------------------------------
// B: per-pixel channel mean / rstd of x
__global__ __launch_bounds__(256) void ln_stats(const float* __restrict__ x,
                                                float* __restrict__ mean,
                                                float* __restrict__ rstd) {
    const int p = blockIdx.x * blockDim.x + threadIdx.x;   // 0..65535
    const int b = p >> 12, hw = p & 4095;
    const float* xp = x + (size_t)b * CCH * HWN + hw;
    float sum = 0.f, ss = 0.f;
#pragma unroll 8
    for (int c = 0; c < CCH; ++c) {
        const float v = xp[(size_t)c * HWN];
        sum += v; ss += v * v;
    }
    const float m = sum * (1.f / 512.f);
    float var = ss * (1.f / 512.f) - m * m;
    var = fmaxf(var, 0.f);
    mean[p] = m;
    rstd[p] = rsqrtf(var + LN_EPS);
}

// ---------------------------------------------------------------------------
// C: qkv[o,p] = rstd[p] * ( sum_c wg[o,c]*x[c,p] - mean[p]*s[o] )
// 128x128x16 fp32 SGEMM, 256 threads, 8x8 micro-tile
__global__ __launch_bounds__(256) void qkv_gemm(const float* __restrict__ x,
                                                const float* __restrict__ wg,
                                                const float* __restrict__ s,
                                                const float* __restrict__ mean,
                                                const float* __restrict__ rstd,
                                                float* __restrict__ qkv) {
    __shared__ float As[16][132];   // padded: transposed stores conflict-free
    __shared__ float Bs[16][128];

    const int tid = threadIdx.x;
    const int om  = blockIdx.y * 128;
    const int pn  = blockIdx.x * 128;
    const int b   = pn >> 12;
    const int hw0 = pn & 4095;
    const float* xb = x + (size_t)b * CCH * HWN + hw0;

    const int tx = tid & 15, ty = tid >> 4;
    float acc[8][8];
#pragma unroll
    for (int i = 0; i < 8; ++i)
#pragma unroll
        for (int j = 0; j < 8; ++j) acc[i][j] = 0.f;

    const int la_c = (tid & 3) * 4;   // 0,4,8,12
    const int la_m = tid >> 2;        // 0..63
    const int lb_k = tid >> 5;        // 0..7
    const int lb_n = (tid & 31) * 4;  // 0..124

    for (int kc = 0; kc < CCH; kc += 16) {
        const float4 a0 = *(const float4*)(wg + (size_t)(om + la_m) * CCH + kc + la_c);
        const float4 a1 = *(const float4*)(wg + (size_t)(om + la_m + 64) * CCH + kc + la_c);
        const float4 b0 = *(const float4*)(xb + (size_t)(kc + lb_k) * HWN + lb_n);
        const float4 b1 = *(const float4*)(xb + (size_t)(kc + lb_k + 8) * HWN + lb_n);
        __syncthreads();
        As[la_c + 0][la_m] = a0.x; As[la_c + 1][la_m] = a0.y;
        As[la_c + 2][la_m] = a0.z; As[la_c + 3][la_m] = a0.w;
        As[la_c + 0][la_m + 64] = a1.x; As[la_c + 1][la_m + 64] = a1.y;
        As[la_c + 2][la_m + 64] = a1.z; As[la_c + 3][la_m + 64] = a1.w;
        *(float4*)&Bs[lb_k][lb_n]     = b0;
        *(float4*)&Bs[lb_k + 8][lb_n] = b1;
        __syncthreads();
#pragma unroll
        for (int k = 0; k < 16; ++k) {
            float av[8], bv[8];
            *(float4*)&av[0] = *(const float4*)&As[k][ty * 8];
            *(float4*)&av[4] = *(const float4*)&As[k][ty * 8 + 4];
            *(float4*)&bv[0] = *(const float4*)&Bs[k][tx * 8];
            *(float4*)&bv[4] = *(const float4*)&Bs[k][tx * 8 + 4];
#pragma unroll
            for (int i = 0; i < 8; ++i)
#pragma unroll
                for (int j = 0; j < 8; ++j)
                    acc[i][j] = fmaf(av[i], bv[j], acc[i][j]);
        }
    }

    float sv[8], mn[8], rs[8];
#pragma unroll
    for (int i = 0; i < 8; ++i) sv[i] = s[om + ty * 8 + i];
#pragma unroll
    for (int j = 0; j < 8; ++j) {
        const int p = pn + tx * 8 + j;
        mn[j] = mean[p]; rs[j] = rstd[p];
    }
#pragma unroll
    for (int i = 0; i < 8; ++i) {
        const int o = om + ty * 8 + i;
        float* dst = qkv + ((size_t)b * OC3 + o) * HWN + hw0 + tx * 8;
        const float ms = sv[i];
        float4 v0, v1;
        v0.x = rs[0] * (acc[i][0] - mn[0] * ms);
        v0.y = rs[1] * (acc[i][1] - mn[1] * ms);
        v0.z = rs[2] * (acc[i][2] - mn[2] * ms);
        v0.w = rs[3] * (acc[i][3] - mn[3] * ms);
        v1.x = rs[4] * (acc[i][4] - mn[4] * ms);
        v1.y = rs[5] * (acc[i][5] - mn[5] * ms);
        v1.z = rs[6] * (acc[i][6] - mn[6] * ms);
        v1.w = rs[7] * (acc[i][7] - mn[7] * ms);
        *(float4*)dst       = v0;
        *(float4*)(dst + 4) = v1;
    }
}

// ---------------------------------------------------------------------------
// D1: per-row (over n=4096) max and 1/sum(exp) for k
__global__ __launch_bounds__(256) void k_stats(const float* __restrict__ qkv,
                                               float* __restrict__ kmax,
                                               float* __restrict__ ksc) {
    const int bx = blockIdx.x;          // 0..255
    const int bh = bx >> 1, half = bx & 1;
    const int b = bh >> 3, h = bh & 7;
    const int lane = threadIdx.x & 63;
    const int w = threadIdx.x >> 6;
    const float* kbase = qkv + ((size_t)b * OC3 + CCH + h * DIMH) * HWN;
    const int r0 = half * 32 + w * 8;
    for (int r = r0; r < r0 + 8; ++r) {
        const float* row = kbase + (size_t)r * HWN;
        float vals[64];
#pragma unroll
        for (int j = 0; j < 64; ++j) vals[j] = row[lane + j * 64];
        float mx = -1e30f;
#pragma unroll
        for (int j = 0; j < 64; ++j) mx = fmaxf(mx, vals[j]);
        mx = waveReduceMax(mx);
        float sum = 0.f;
#pragma unroll
        for (int j = 0; j < 64; ++j) sum += __expf(vals[j] - mx);
        sum = waveReduceSum(sum);
        if (lane == 0) {
            kmax[bh * 64 + r] = mx;
            ksc[bh * 64 + r]  = 1.0f / sum;
        }
    }
}

// ---------------------------------------------------------------------------
// D2: partial context over an n-chunk of 512:
//     ctp[bh,ci,d,e] = sum_n ktilde[d,n] * vtilde[e,n]
__global__ __launch_bounds__(256) void ctx_partial(const float* __restrict__ qkv,
                                                   const float* __restrict__ kmax,
                                                   const float* __restrict__ ksc,
                                                   float* __restrict__ ctp) {
    __shared__ float kt[64][68];   // [n][d]
    __shared__ float vt[64][68];
    __shared__ float kmx[64], kss[64];

    const int bh = blockIdx.y, ci = blockIdx.x;
    const int b = bh >> 3, h = bh & 7;
    const float* kb = qkv + ((size_t)b * OC3 + CCH  + h * DIMH) * HWN;
    const float* vb = qkv + ((size_t)b * OC3 + 1024 + h * DIMH) * HWN;
    const int tid = threadIdx.x;
    if (tid < 64) { kmx[tid] = kmax[bh * 64 + tid]; kss[tid] = ksc[bh * 64 + tid]; }

    const int d  = tid >> 2;          // 0..63
    const int nq = (tid & 3) * 4;     // 0,4,8,12
    const int td = tid & 15, te = tid >> 4;
    float acc[4][4];
#pragma unroll
    for (int i = 0; i < 4; ++i)
#pragma unroll
        for (int j = 0; j < 4; ++j) acc[i][j] = 0.f;

    for (int t = 0; t < 8; ++t) {
        const int n0 = ci * 512 + t * 64;
        __syncthreads();   // guard prev compute & first-iter stats
        const float m = kmx[d], sc = kss[d];
#pragma unroll
        for (int jj = 0; jj < 4; ++jj) {
            const int nn = nq + jj * 16;
            const float4 kv = *(const float4*)(kb + (size_t)d * HWN + n0 + nn);
            const float4 vv = *(const float4*)(vb + (size_t)d * HWN + n0 + nn);
            kt[nn + 0][d] = __expf(kv.x - m) * sc;
            kt[nn + 1][d] = __expf(kv.y - m) * sc;
            kt[nn + 2][d] = __expf(kv.z - m) * sc;
            kt[nn + 3][d] = __expf(kv.w - m) * sc;
            vt[nn + 0][d] = vv.x * (1.f / 4096.f);
            vt[nn + 1][d] = vv.y * (1.f / 4096.f);
            vt[nn + 2][d] = vv.z * (1.f / 4096.f);
            vt[nn + 3][d] = vv.w * (1.f / 4096.f);
        }
        __syncthreads();
#pragma unroll
        for (int nn = 0; nn < 64; ++nn) {
            float kf[4], vf[4];
            *(float4*)kf = *(const float4*)&kt[nn][td * 4];
            *(float4*)vf = *(const float4*)&vt[nn][te * 4];
#pragma unroll
            for (int i = 0; i < 4; ++i)
#pragma unroll
                for (int j = 0; j < 4; ++j)
                    acc[i][j] = fmaf(kf[i], vf[j], acc[i][j]);
        }
    }
    float* dst = ctp + ((size_t)bh * 8 + ci) * 4096;
#pragma unroll
    for (int i = 0; i < 4; ++i) {
        const float4 o4 = make_float4(acc[i][0], acc[i][1], acc[i][2], acc[i][3]);
        *(float4*)(dst + (td * 4 + i) * 64 + te * 4) = o4;
    }
}

// ---------------------------------------------------------------------------
// D3: ct[bh,d,e] = sum_ci ctp[bh,ci,d,e]
__global__ __launch_bounds__(256) void ctx_reduce(const float* __restrict__ ctp,
                                                  float* __restrict__ ct) {
    const int bh = blockIdx.x;
    const int tid = threadIdx.x;
    const float* src = ctp + (size_t)bh * 8 * 4096;
    float* dst = ct + (size_t)bh * 4096;
    for (int e4 = tid * 4; e4 < 4096; e4 += 1024) {
        float4 sum = make_float4(0.f, 0.f, 0.f, 0.f);
#pragma unroll
        for (int ci = 0; ci < 8; ++ci) {
            const float4 v = *(const float4*)(src + (size_t)ci * 4096 + e4);
            sum.x += v.x; sum.y += v.y; sum.z += v.z; sum.w += v.w;
        }
        *(float4*)(dst + e4) = sum;
    }
}

// ---------------------------------------------------------------------------
// D4: q-softmax (over d) * SCALE, then out[e,n] = sum_d ct[d,e]*qtilde[d,n]
//     writes attention output into d_out (scratch)
__global__ __launch_bounds__(256) void attn_out(const float* __restrict__ qkv,
                                                const float* __restrict__ ct,
                                                float* __restrict__ aout) {
    __shared__ float cts[64][68];   // [d][e]
    __shared__ float qt[64][68];    // [n][d]
    __shared__ float qmx[64], qsc[64];

    const int bh = blockIdx.y, ci = blockIdx.x;
    const int b = bh >> 3, h = bh & 7;
    const float* qb = qkv + ((size_t)b * OC3 + h * DIMH) * HWN;
    const int tid = threadIdx.x;

    for (int i4 = tid * 4; i4 < 4096; i4 += 1024) {
        const float4 v = *(const float4*)(ct + (size_t)bh * 4096 + i4);
        *(float4*)&cts[i4 >> 6][i4 & 63] = v;
    }

    const int d  = tid >> 2;
    const int nq = (tid & 3) * 4;
    const int te = tid & 15, tn = tid >> 4;

    for (int t = 0; t < 8; ++t) {
        const int n0 = ci * 512 + t * 64;
        __syncthreads();   // guard prev compute + first-iter cts load
#pragma unroll
        for (int jj = 0; jj < 4; ++jj) {
            const int nn = nq + jj * 16;
            const float4 qv = *(const float4*)(qb + (size_t)d * HWN + n0 + nn);
            qt[nn + 0][d] = qv.x; qt[nn + 1][d] = qv.y;
            qt[nn + 2][d] = qv.z; qt[nn + 3][d] = qv.w;
        }
        __syncthreads();
        if (tid < 64) {
            float mx = -1e30f;
            for (int d2 = 0; d2 < 64; ++d2) {
                const int dd = (d2 + tid) & 63;   // rotate to dodge bank conflicts
                mx = fmaxf(mx, qt[tid][dd]);
            }
            float sm = 0.f;
            for (int d2 = 0; d2 < 64; ++d2) {
                const int dd = (d2 + tid) & 63;
                sm += __expf(qt[tid][dd] - mx);
            }
            qmx[tid] = mx;
            qsc[tid] = QSCALE / sm;
        }
        __syncthreads();
        {
            const int nn = tid >> 2;
            const int d0 = (tid & 3) * 16;
            const float m = qmx[nn], sc = qsc[nn];
#pragma unroll
            for (int dd = 0; dd < 16; ++dd)
                qt[nn][d0 + dd] = __expf(qt[nn][d0 + dd] - m) * sc;
        }
        __syncthreads();
        float acc[4][4];
#pragma unroll
        for (int i = 0; i < 4; ++i)
#pragma unroll
            for (int j = 0; j < 4; ++j) acc[i][j] = 0.f;
#pragma unroll
        for (int dd = 0; dd < 64; ++dd) {
            float cv[4];
            *(float4*)cv = *(const float4*)&cts[dd][te * 4];
            const float q0 = qt[tn * 4 + 0][dd];
            const float q1 = qt[tn * 4 + 1][dd];
            const float q2 = qt[tn * 4 + 2][dd];
            const float q3 = qt[tn * 4 + 3][dd];
#pragma unroll
            for (int i = 0; i < 4; ++i) {
                acc[i][0] = fmaf(cv[i], q0, acc[i][0]);
                acc[i][1] = fmaf(cv[i], q1, acc[i][1]);
                acc[i][2] = fmaf(cv[i], q2, acc[i][2]);
                acc[i][3] = fmaf(cv[i], q3, acc[i][3]);
            }
        }
#pragma unroll
        for (int i = 0; i < 4; ++i) {
            const float4 o4 = make_float4(acc[i][0], acc[i][1], acc[i][2], acc[i][3]);
            *(float4*)(aout + ((size_t)b * CCH + h * DIMH + te * 4 + i) * HWN + n0 + tn * 4) = o4;
        }
    }
}

// ---------------------------------------------------------------------------
// E: y = w_out @ attn + b_out; out = LN_ch(y)*g_out + x  (in-place on d_out)
// block: 64 pixels x all 512 channels; 512 threads, 8x8 micro-tile
__global__ __launch_bounds__(512) void out_gemm_ln(const float* __restrict__ w_out,
                                                   const float* __restrict__ b_out,
                                                   const float* __restrict__ g_out,
                                                   const float* __restrict__ x,
                                                   float* io) {
    __shared__ float smf[9280];                          // 37120 B, reused
    float (*As)[516] = (float (*)[516])smf;              // 16 x 516
    float (*Bs)[64]  = (float (*)[64])(smf + 16 * 516);  // 16 x 64
    float (*ps)[65]  = (float (*)[65])smf;               // 64 x 65 (reuse)
    float (*ps2)[65] = (float (*)[65])(smf + 64 * 65);
    __shared__ float mnE[64], rsE[64];

    const int tid = threadIdx.x;
    const int p0  = blockIdx.x * 64;
    const int b   = p0 >> 12;
    const int hw0 = p0 & 4095;
    const float* aob = io + (size_t)b * CCH * HWN + hw0;

    const int tm = tid >> 3, tn = tid & 7;
    const int m0 = tm * 8, n0 = tn * 8;

    float acc[8][8];
#pragma unroll
    for (int i = 0; i < 8; ++i)
#pragma unroll
        for (int j = 0; j < 8; ++j) acc[i][j] = 0.f;

    const int la_c = (tid & 3) * 4;
    const int la_m = tid >> 2;          // 0..127
    const int lb_k = tid >> 4;          // 0..15 (tid<256)
    const int lb_n = (tid & 15) * 4;

    for (int kc = 0; kc < CCH; kc += 16) {
        float4 a[4];
#pragma unroll
        for (int r = 0; r < 4; ++r)
            a[r] = *(const float4*)(w_out + (size_t)(la_m + 128 * r) * CCH + kc + la_c);
        float4 bv;
        if (tid < 256) bv = *(const float4*)(aob + (size_t)(kc + lb_k) * HWN + lb_n);
        __syncthreads();
#pragma unroll
        for (int r = 0; r < 4; ++r) {
            As[la_c + 0][la_m + 128 * r] = a[r].x;
            As[la_c + 1][la_m + 128 * r] = a[r].y;
            As[la_c + 2][la_m + 128 * r] = a[r].z;
            As[la_c + 3][la_m + 128 * r] = a[r].w;
        }
        if (tid < 256) *(float4*)&Bs[lb_k][lb_n] = bv;
        __syncthreads();
#pragma unroll
        for (int k = 0; k < 16; ++k) {
            float av[8], bw[8];
            *(float4*)&av[0] = *(const float4*)&As[k][m0];
            *(float4*)&av[4] = *(const float4*)&As[k][m0 + 4];
            *(float4*)&bw[0] = *(const float4*)&Bs[k][n0];
            *(float4*)&bw[4] = *(const float4*)&Bs[k][n0 + 4];
#pragma unroll
            for (int i = 0; i < 8; ++i)
#pragma unroll
                for (int j = 0; j < 8; ++j)
                    acc[i][j] = fmaf(av[i], bw[j], acc[i][j]);
        }
    }

    float bb[8], gg[8];
#pragma unroll
    for (int i = 0; i < 8; ++i) { bb[i] = b_out[m0 + i]; gg[i] = g_out[m0 + i]; }
#pragma unroll
    for (int i = 0; i < 8; ++i)
#pragma unroll
        for (int j = 0; j < 8; ++j) acc[i][j] += bb[i];

    __syncthreads();   // done reading As/Bs; reuse smf for reduction
#pragma unroll
    for (int j = 0; j < 8; ++j) {
        float s1 = 0.f, s2 = 0.f;
#pragma unroll
        for (int i = 0; i < 8; ++i) { s1 += acc[i][j]; s2 += acc[i][j] * acc[i][j]; }
        ps[tm][n0 + j]  = s1;
        ps2[tm][n0 + j] = s2;
    }
    __syncthreads();
    if (tid < 64) {
        float s1 = 0.f, s2 = 0.f;
#pragma unroll 8
        for (int t = 0; t < 64; ++t) { s1 += ps[t][tid]; s2 += ps2[t][tid]; }
        const float m = s1 * (1.f / 512.f);
        float var = s2 * (1.f / 512.f) - m * m;
        var = fmaxf(var, 0.f);
        mnE[tid] = m;
        rsE[tid] = rsqrtf(var + LN_EPS);
    }
    __syncthreads();
    float mnl[8], rsl[8];
#pragma unroll
    for (int j = 0; j < 8; ++j) { mnl[j] = mnE[n0 + j]; rsl[j] = rsE[n0 + j]; }
#pragma unroll
    for (int i = 0; i < 8; ++i) {
        const int o = m0 + i;
        const float* xr = x + ((size_t)b * CCH + o) * HWN + hw0 + n0;
        float* dst = io + ((size_t)b * CCH + o) * HWN + hw0 + n0;
        const float4 x0 = *(const float4*)xr;
        const float4 x1 = *(const float4*)(xr + 4);
        float4 o0, o1;
        o0.x = (acc[i][0] - mnl[0]) * rsl[0] * gg[i] + x0.x;
        o0.y = (acc[i][1] - mnl[1]) * rsl[1] * gg[i] + x0.y;
        o0.z = (acc[i][2] - mnl[2]) * rsl[2] * gg[i] + x0.z;
        o0.w = (acc[i][3] - mnl[3]) * rsl[3] * gg[i] + x0.w;
        o1.x = (acc[i][4] - mnl[4]) * rsl[4] * gg[i] + x1.x;
        o1.y = (acc[i][5] - mnl[5]) * rsl[5] * gg[i] + x1.y;
        o1.z = (acc[i][6] - mnl[6]) * rsl[6] * gg[i] + x1.z;
        o1.w = (acc[i][7] - mnl[7]) * rsl[7] * gg[i] + x1.w;
        *(float4*)dst       = o0;
        *(float4*)(dst + 4) = o1;
    }
}

// ---------------------------------------------------------------------------
extern "C" void kernel_launch(void* const* d_in, const int* in_sizes, int n_in,
                              void* d_out, int out_size, void* d_ws, size_t ws_size,
                              hipStream_t stream) {
    (void)in_sizes; (void)n_in; (void)out_size;
    const float* x     = (const float*)d_in[0];
    const float* w_qkv = (const float*)d_in[1];
    const float* w_out = (const float*)d_in[2];
    const float* b_out = (const float*)d_in[3];
    const float* g_out = (const float*)d_in[4];
    const float* g_ln  = (const float*)d_in[5];
    float* out = (float*)d_out;
    float* ws  = (float*)d_ws;

    float* mean = ws;                    // 65536
    float* rstd = mean + NPIX;           // 65536
    float* wg   = rstd + NPIX;           // 1536*512 = 786432
    float* s    = wg + (size_t)OC3 * CCH;     // 1536
    float* kmax = s + OC3;               // 128*64 = 8192
    float* ksc  = kmax + 8192;           // 8192
    float* ctp  = ksc + 8192;            // 128*8*4096 = 4194304
    float* ct   = ctp + 4194304;         // 128*4096 = 524288
    float* qkv  = ct + 524288;           // 16*1536*4096 = 100663296

    const size_t need_floats = (size_t)(qkv - ws) + (size_t)100663296;
    if (ws_size < need_floats * sizeof(float)) return;   // ws too small: no-op

    prep_wg   <<<OC3, 64, 0, stream>>>(w_qkv, g_ln, wg, s);
    ln_stats  <<<NPIX / 256, 256, 0, stream>>>(x, mean, rstd);
    qkv_gemm  <<<dim3(512, 12), 256, 0, stream>>>(x, wg, s, mean, rstd, qkv);
    k_stats   <<<256, 256, 0, stream>>>(qkv, kmax, ksc);
    ctx_partial<<<dim3(8, 128), 256, 0, stream>>>(qkv, kmax, ksc, ctp);
    ctx_reduce<<<128, 256, 0, stream>>>(ctp, ct);
    attn_out  <<<dim3(8, 128), 256, 0, stream>>>(qkv, ct, out);
    out_gemm_ln<<<1024, 512, 0, stream>>>(w_out, b_out, g_out, x, out);
}

// Round 3
// 956.274 us; speedup vs baseline: 1.9311x; 1.9311x over previous
//
#include <hip/hip_runtime.h>
#include <math.h>

#define CCH    512
#define HWN    4096
#define NPIX   65536
#define OC3    1536
#define QSCALE 0.125f
#define LN_EPS 1e-5f

typedef _Float16 h16;
typedef h16  f16x8 __attribute__((ext_vector_type(8)));
typedef float f32x4 __attribute__((ext_vector_type(4)));

__device__ __forceinline__ float waveReduceSum(float v) {
#pragma unroll
    for (int off = 32; off; off >>= 1) v += __shfl_xor(v, off);
    return v;
}
__device__ __forceinline__ float waveReduceMax(float v) {
#pragma unroll
    for (int off = 32; off; off >>= 1) v = fmaxf(v, __shfl_xor(v, off));
    return v;
}

__device__ __forceinline__ void gl_lds16(const void* g, void* l) {
    __builtin_amdgcn_global_load_lds((const __attribute__((address_space(1))) void*)g,
                                     (__attribute__((address_space(3))) void*)l, 16, 0, 0);
}

// ---------------------------------------------------------------------------
// wg[o,c] = w_qkv[o,c]*g_ln[c] -> fp16 hi/lo; s[o] = sum_c wg[o,c]
__global__ __launch_bounds__(64) void prep_wg(const float* __restrict__ w_qkv,
                                              const float* __restrict__ g_ln,
                                              h16* __restrict__ wh, h16* __restrict__ wl,
                                              float* __restrict__ s) {
    const int o = blockIdx.x, lane = threadIdx.x;
    float sum = 0.f;
#pragma unroll
    for (int j = 0; j < 8; ++j) {
        const int c = lane + j * 64;
        const float w = w_qkv[(size_t)o * CCH + c] * g_ln[c];
        const h16 hi = (h16)w;
        wh[(size_t)o * CCH + c] = hi;
        wl[(size_t)o * CCH + c] = (h16)(w - (float)hi);
        sum += w;
    }
    sum = waveReduceSum(sum);
    if (lane == 0) s[o] = sum;
}

__global__ __launch_bounds__(64) void prep_wo(const float* __restrict__ w_out,
                                              h16* __restrict__ wh, h16* __restrict__ wl) {
    const int o = blockIdx.x, lane = threadIdx.x;
#pragma unroll
    for (int j = 0; j < 8; ++j) {
        const int c = lane + j * 64;
        const float w = w_out[(size_t)o * CCH + c];
        const h16 hi = (h16)w;
        wh[(size_t)o * CCH + c] = hi;
        wl[(size_t)o * CCH + c] = (h16)(w - (float)hi);
    }
}

// ---------------------------------------------------------------------------
// per-pixel channel mean / rstd of x
__global__ __launch_bounds__(256) void ln_stats(const float* __restrict__ x,
                                                float* __restrict__ mean,
                                                float* __restrict__ rstd) {
    const int p = blockIdx.x * blockDim.x + threadIdx.x;
    const int b = p >> 12, hw = p & 4095;
    const float* xp = x + (size_t)b * CCH * HWN + hw;
    float sum = 0.f, ss = 0.f;
#pragma unroll 8
    for (int c = 0; c < CCH; ++c) {
        const float v = xp[(size_t)c * HWN];
        sum += v; ss += v * v;
    }
    const float m = sum * (1.f / 512.f);
    float var = ss * (1.f / 512.f) - m * m;
    var = fmaxf(var, 0.f);
    mean[p] = m;
    rstd[p] = rsqrtf(var + LN_EPS);
}

// ---------------------------------------------------------------------------
// fp32 [16][512][4096] -> transposed fp16 hi/lo [16][4096][512]
__global__ __launch_bounds__(256) void transpose_cvt(const float* __restrict__ src,
                                                     h16* __restrict__ dhi,
                                                     h16* __restrict__ dlo) {
    __shared__ float tile[64][65];
    const int b = blockIdx.z, c0 = blockIdx.y * 64, p0 = blockIdx.x * 64;
    const int t = threadIdx.x;
    const float* sb = src + ((size_t)b * CCH + c0) * HWN + p0;
    const int rc = t >> 4, cc4 = (t & 15) * 4;
#pragma unroll
    for (int ps = 0; ps < 4; ++ps) {
        const float4 v = *(const float4*)(sb + (size_t)(rc + ps * 16) * HWN + cc4);
        tile[rc + ps * 16][cc4 + 0] = v.x;
        tile[rc + ps * 16][cc4 + 1] = v.y;
        tile[rc + ps * 16][cc4 + 2] = v.z;
        tile[rc + ps * 16][cc4 + 3] = v.w;
    }
    __syncthreads();
    const int pr0 = t >> 3, cs = (t & 7) * 8;
#pragma unroll
    for (int ps = 0; ps < 2; ++ps) {
        const int pr = pr0 + ps * 32;
        f16x8 vh, vl;
#pragma unroll
        for (int q = 0; q < 8; ++q) {
            const float v = tile[cs + q][pr];
            const h16 hi = (h16)v;
            vh[q] = hi;
            vl[q] = (h16)(v - (float)hi);
        }
        const size_t o = ((size_t)b * HWN + p0 + pr) * CCH + c0 + cs;
        *(f16x8*)(dhi + o) = vh;
        *(f16x8*)(dlo + o) = vl;
    }
}

// ---------------------------------------------------------------------------
// 128x128 MFMA GEMM, fp16 split-3, K=512.
// A (hi/lo): [M][512] K-contig. B (hi/lo): [p][512] K-contig (pre-transposed).
// QKV epilogue: rstd[p]*(acc - mean[p]*s[o]) ; else: acc + bias[o].
template <int OCT, bool QKV>
__global__ __launch_bounds__(256) void gemm128(const h16* __restrict__ Ahg,
                                               const h16* __restrict__ Alg,
                                               const h16* __restrict__ Bhg,
                                               const h16* __restrict__ Blg,
                                               const float* __restrict__ sv,
                                               const float* __restrict__ mean,
                                               const float* __restrict__ rstd,
                                               float* __restrict__ outp) {
    __shared__ __align__(16) h16 Ah[4096], Al[4096], Bh[4096], Bl[4096];
    const int tid = threadIdx.x;
    const int om = blockIdx.y * 128;
    const int p0 = blockIdx.x * 128;

    // staging: thread t -> LDS halfword offset t*8 (linear, [128][32] row-major);
    // global source k-slot XOR-swizzled by dest row (slot^row&3) so ds_read can
    // un-swizzle -> minimum (8 dword-accesses/bank) on ds_read_b128.
    const int srow = tid >> 2;
    const int skh  = ((tid & 3) ^ (srow & 3)) * 8;
    const size_t a0 = (size_t)(om + srow) * CCH + skh;
    const size_t b0 = (size_t)(p0 + srow) * CCH + skh;
    const int wofs = (tid >> 6) * 512;   // wave-uniform LDS base (halfs)

    const int lane = tid & 63;
    const int wv = tid >> 6;
    const int wm = (wv >> 1) * 64, wn = (wv & 1) * 64;
    const int lr = lane & 15, kg = lane >> 4;
    const int swz = (kg ^ (lr & 3)) * 8;

    f32x4 acc[4][4];
#pragma unroll
    for (int i = 0; i < 4; ++i)
#pragma unroll
        for (int j = 0; j < 4; ++j) acc[i][j] = {0.f, 0.f, 0.f, 0.f};

#define STAGE(KC)                                               \
    do {                                                        \
        gl_lds16(Ahg + a0 + (KC), Ah + wofs);                   \
        gl_lds16(Ahg + a0 + (KC) + 64 * CCH, Ah + 2048 + wofs); \
        gl_lds16(Alg + a0 + (KC), Al + wofs);                   \
        gl_lds16(Alg + a0 + (KC) + 64 * CCH, Al + 2048 + wofs); \
        gl_lds16(Bhg + b0 + (KC), Bh + wofs);                   \
        gl_lds16(Bhg + b0 + (KC) + 64 * CCH, Bh + 2048 + wofs); \
        gl_lds16(Blg + b0 + (KC), Bl + wofs);                   \
        gl_lds16(Blg + b0 + (KC) + 64 * CCH, Bl + 2048 + wofs); \
    } while (0)

    STAGE(0);
#pragma unroll 1
    for (int kc = 0; kc < 512; kc += 32) {
        __syncthreads();   // staged tile visible (vmcnt drained by barrier)
        f16x8 ah[4], al[4], bh[4], bl[4];
#pragma unroll
        for (int i = 0; i < 4; ++i) {
            const int ra = (wm + i * 16 + lr) * 32 + swz;
            ah[i] = *(const f16x8*)(Ah + ra);
            al[i] = *(const f16x8*)(Al + ra);
            const int rb = (wn + i * 16 + lr) * 32 + swz;
            bh[i] = *(const f16x8*)(Bh + rb);
            bl[i] = *(const f16x8*)(Bl + rb);
        }
        __syncthreads();   // all frag reads done; safe to overwrite LDS
        if (kc + 32 < 512) STAGE(kc + 32);   // async loads overlap MFMA below
#pragma unroll
        for (int i = 0; i < 4; ++i)
#pragma unroll
            for (int j = 0; j < 4; ++j) {
                acc[i][j] = __builtin_amdgcn_mfma_f32_16x16x32_f16(ah[i], bh[j], acc[i][j], 0, 0, 0);
                acc[i][j] = __builtin_amdgcn_mfma_f32_16x16x32_f16(ah[i], bl[j], acc[i][j], 0, 0, 0);
                acc[i][j] = __builtin_amdgcn_mfma_f32_16x16x32_f16(al[i], bh[j], acc[i][j], 0, 0, 0);
            }
    }
#undef STAGE

    // C/D layout: col = lane&15 (n), row = (lane>>4)*4 + reg (m)
    const int b = p0 >> 12, hw0 = p0 & 4095;
    if constexpr (QKV) {
        float mn[4], rs[4];
#pragma unroll
        for (int j = 0; j < 4; ++j) {
            const int p = p0 + wn + j * 16 + lr;
            mn[j] = mean[p]; rs[j] = rstd[p];
        }
#pragma unroll
        for (int i = 0; i < 4; ++i)
#pragma unroll
            for (int r = 0; r < 4; ++r) {
                const int o = om + wm + i * 16 + kg * 4 + r;
                const float so = sv[o];
                float* dst = outp + ((size_t)b * OCT + o) * HWN;
#pragma unroll
                for (int j = 0; j < 4; ++j) {
                    const int hw = hw0 + wn + j * 16 + lr;
                    dst[hw] = rs[j] * (acc[i][j][r] - mn[j] * so);
                }
            }
    } else {
#pragma unroll
        for (int i = 0; i < 4; ++i)
#pragma unroll
            for (int r = 0; r < 4; ++r) {
                const int o = om + wm + i * 16 + kg * 4 + r;
                const float bias = sv[o];
                float* dst = outp + ((size_t)b * OCT + o) * HWN;
#pragma unroll
                for (int j = 0; j < 4; ++j) {
                    const int hw = hw0 + wn + j * 16 + lr;
                    dst[hw] = acc[i][j][r] + bias;
                }
            }
    }
}

// ---------------------------------------------------------------------------
// per-row (over n=4096) max and 1/sum(exp) for k
__global__ __launch_bounds__(256) void k_stats(const float* __restrict__ qkv,
                                               float* __restrict__ kmax,
                                               float* __restrict__ ksc) {
    const int bx = blockIdx.x;
    const int bh = bx >> 1, half = bx & 1;
    const int b = bh >> 3, h = bh & 7;
    const int lane = threadIdx.x & 63;
    const int w = threadIdx.x >> 6;
    const float* kbase = qkv + ((size_t)b * OC3 + CCH + h * 64) * HWN;
    const int r0 = half * 32 + w * 8;
    for (int r = r0; r < r0 + 8; ++r) {
        const float* row = kbase + (size_t)r * HWN;
        float vals[64];
#pragma unroll
        for (int j = 0; j < 64; ++j) vals[j] = row[lane + j * 64];
        float mx = -1e30f;
#pragma unroll
        for (int j = 0; j < 64; ++j) mx = fmaxf(mx, vals[j]);
        mx = waveReduceMax(mx);
        float sum = 0.f;
#pragma unroll
        for (int j = 0; j < 64; ++j) sum += __expf(vals[j] - mx);
        sum = waveReduceSum(sum);
        if (lane == 0) {
            kmax[bh * 64 + r] = mx;
            ksc[bh * 64 + r]  = 1.0f / sum;
        }
    }
}

// ---------------------------------------------------------------------------
// partial context over an n-chunk of 1024
__global__ __launch_bounds__(256) void ctx_partial(const float* __restrict__ qkv,
                                                   const float* __restrict__ kmax,
                                                   const float* __restrict__ ksc,
                                                   float* __restrict__ ctp) {
    __shared__ float kt[64][68];
    __shared__ float vt[64][68];
    __shared__ float kmx[64], kss[64];

    const int bh = blockIdx.y, ci = blockIdx.x;
    const int b = bh >> 3, h = bh & 7;
    const float* kb = qkv + ((size_t)b * OC3 + CCH  + h * 64) * HWN;
    const float* vb = qkv + ((size_t)b * OC3 + 1024 + h * 64) * HWN;
    const int tid = threadIdx.x;
    if (tid < 64) { kmx[tid] = kmax[bh * 64 + tid]; kss[tid] = ksc[bh * 64 + tid]; }

    const int d  = tid >> 2;
    const int nq = (tid & 3) * 4;
    const int td = tid & 15, te = tid >> 4;
    float acc[4][4];
#pragma unroll
    for (int i = 0; i < 4; ++i)
#pragma unroll
        for (int j = 0; j < 4; ++j) acc[i][j] = 0.f;

    for (int t = 0; t < 16; ++t) {
        const int n0 = ci * 1024 + t * 64;
        __syncthreads();
        const float m = kmx[d], sc = kss[d];
#pragma unroll
        for (int jj = 0; jj < 4; ++jj) {
            const int nn = nq + jj * 16;
            const float4 kv = *(const float4*)(kb + (size_t)d * HWN + n0 + nn);
            const float4 vv = *(const float4*)(vb + (size_t)d * HWN + n0 + nn);
            kt[nn + 0][d] = __expf(kv.x - m) * sc;
            kt[nn + 1][d] = __expf(kv.y - m) * sc;
            kt[nn + 2][d] = __expf(kv.z - m) * sc;
            kt[nn + 3][d] = __expf(kv.w - m) * sc;
            vt[nn + 0][d] = vv.x * (1.f / 4096.f);
            vt[nn + 1][d] = vv.y * (1.f / 4096.f);
            vt[nn + 2][d] = vv.z * (1.f / 4096.f);
            vt[nn + 3][d] = vv.w * (1.f / 4096.f);
        }
        __syncthreads();
#pragma unroll
        for (int nn = 0; nn < 64; ++nn) {
            float kf[4], vf[4];
            *(float4*)kf = *(const float4*)&kt[nn][td * 4];
            *(float4*)vf = *(const float4*)&vt[nn][te * 4];
#pragma unroll
            for (int i = 0; i < 4; ++i)
#pragma unroll
                for (int j = 0; j < 4; ++j)
                    acc[i][j] = fmaf(kf[i], vf[j], acc[i][j]);
        }
    }
    float* dst = ctp + ((size_t)bh * 4 + ci) * 4096;
#pragma unroll
    for (int i = 0; i < 4; ++i) {
        const float4 o4 = make_float4(acc[i][0], acc[i][1], acc[i][2], acc[i][3]);
        *(float4*)(dst + (td * 4 + i) * 64 + te * 4) = o4;
    }
}

__global__ __launch_bounds__(256) void ctx_reduce(const float* __restrict__ ctp,
                                                  float* __restrict__ ct) {
    const int bh = blockIdx.x;
    const int tid = threadIdx.x;
    const float* src = ctp + (size_t)bh * 4 * 4096;
    float* dst = ct + (size_t)bh * 4096;
    for (int e4 = tid * 4; e4 < 4096; e4 += 1024) {
        float4 sum = make_float4(0.f, 0.f, 0.f, 0.f);
#pragma unroll
        for (int ci = 0; ci < 4; ++ci) {
            const float4 v = *(const float4*)(src + (size_t)ci * 4096 + e4);
            sum.x += v.x; sum.y += v.y; sum.z += v.z; sum.w += v.w;
        }
        *(float4*)(dst + e4) = sum;
    }
}

// ---------------------------------------------------------------------------
// q-softmax(d)*SCALE, out[e,n] = sum_d ct[d,e]*qtilde[d,n]  -> aout (d_out)
__global__ __launch_bounds__(256) void attn_out(const float* __restrict__ qkv,
                                                const float* __restrict__ ct,
                                                float* __restrict__ aout) {
    __shared__ float cts[64][68];
    __shared__ float qt[64][68];
    __shared__ float qmx[64], qsc[64];

    const int bh = blockIdx.y, ci = blockIdx.x;
    const int b = bh >> 3, h = bh & 7;
    const float* qb = qkv + ((size_t)b * OC3 + h * 64) * HWN;
    const int tid = threadIdx.x;

    for (int i4 = tid * 4; i4 < 4096; i4 += 1024) {
        const float4 v = *(const float4*)(ct + (size_t)bh * 4096 + i4);
        *(float4*)&cts[i4 >> 6][i4 & 63] = v;
    }

    const int d  = tid >> 2;
    const int nq = (tid & 3) * 4;
    const int te = tid & 15, tn = tid >> 4;

    for (int t = 0; t < 8; ++t) {
        const int n0 = ci * 512 + t * 64;
        __syncthreads();
#pragma unroll
        for (int jj = 0; jj < 4; ++jj) {
            const int nn = nq + jj * 16;
            const float4 qv = *(const float4*)(qb + (size_t)d * HWN + n0 + nn);
            qt[nn + 0][d] = qv.x; qt[nn + 1][d] = qv.y;
            qt[nn + 2][d] = qv.z; qt[nn + 3][d] = qv.w;
        }
        __syncthreads();
        if (tid < 64) {
            float mx = -1e30f;
            for (int d2 = 0; d2 < 64; ++d2) {
                const int dd = (d2 + tid) & 63;
                mx = fmaxf(mx, qt[tid][dd]);
            }
            float sm = 0.f;
            for (int d2 = 0; d2 < 64; ++d2) {
                const int dd = (d2 + tid) & 63;
                sm += __expf(qt[tid][dd] - mx);
            }
            qmx[tid] = mx;
            qsc[tid] = QSCALE / sm;
        }
        __syncthreads();
        {
            const int nn = tid >> 2;
            const int d0 = (tid & 3) * 16;
            const float m = qmx[nn], sc = qsc[nn];
#pragma unroll
            for (int dd = 0; dd < 16; ++dd)
                qt[nn][d0 + dd] = __expf(qt[nn][d0 + dd] - m) * sc;
        }
        __syncthreads();
        float acc[4][4];
#pragma unroll
        for (int i = 0; i < 4; ++i)
#pragma unroll
            for (int j = 0; j < 4; ++j) acc[i][j] = 0.f;
#pragma unroll
        for (int dd = 0; dd < 64; ++dd) {
            float cv[4];
            *(float4*)cv = *(const float4*)&cts[dd][te * 4];
            const float q0 = qt[tn * 4 + 0][dd];
            const float q1 = qt[tn * 4 + 1][dd];
            const float q2 = qt[tn * 4 + 2][dd];
            const float q3 = qt[tn * 4 + 3][dd];
#pragma unroll
            for (int i = 0; i < 4; ++i) {
                acc[i][0] = fmaf(cv[i], q0, acc[i][0]);
                acc[i][1] = fmaf(cv[i], q1, acc[i][1]);
                acc[i][2] = fmaf(cv[i], q2, acc[i][2]);
                acc[i][3] = fmaf(cv[i], q3, acc[i][3]);
            }
        }
#pragma unroll
        for (int i = 0; i < 4; ++i) {
            const float4 o4 = make_float4(acc[i][0], acc[i][1], acc[i][2], acc[i][3]);
            *(float4*)(aout + ((size_t)b * CCH + h * 64 + te * 4 + i) * HWN + n0 + tn * 4) = o4;
        }
    }
}

// ---------------------------------------------------------------------------
// out = LN_ch(y)*g_out + x   (y already contains bias)
__global__ __launch_bounds__(256) void final_ln(const float* __restrict__ y,
                                                const float* __restrict__ x,
                                                const float* __restrict__ g_out,
                                                float* __restrict__ out) {
    const int p = blockIdx.x * 256 + threadIdx.x;
    const int b = p >> 12, hw = p & 4095;
    const float* yp = y + (size_t)b * CCH * HWN + hw;
    const float* xp = x + (size_t)b * CCH * HWN + hw;
    float* op = out + (size_t)b * CCH * HWN + hw;
    float s1 = 0.f, s2 = 0.f;
#pragma unroll 8
    for (int c = 0; c < CCH; ++c) {
        const float v = yp[(size_t)c * HWN];
        s1 += v; s2 += v * v;
    }
    const float m = s1 * (1.f / 512.f);
    float var = s2 * (1.f / 512.f) - m * m;
    var = fmaxf(var, 0.f);
    const float rs = rsqrtf(var + LN_EPS);
#pragma unroll 8
    for (int c = 0; c < CCH; ++c)
        op[(size_t)c * HWN] = (yp[(size_t)c * HWN] - m) * rs * g_out[c] + xp[(size_t)c * HWN];
}

// ---------------------------------------------------------------------------
extern "C" void kernel_launch(void* const* d_in, const int* in_sizes, int n_in,
                              void* d_out, int out_size, void* d_ws, size_t ws_size,
                              hipStream_t stream) {
    (void)in_sizes; (void)n_in; (void)out_size;
    const float* x     = (const float*)d_in[0];
    const float* w_qkv = (const float*)d_in[1];
    const float* w_out = (const float*)d_in[2];
    const float* b_out = (const float*)d_in[3];
    const float* g_out = (const float*)d_in[4];
    const float* g_ln  = (const float*)d_in[5];
    float* out = (float*)d_out;
    float* ws  = (float*)d_ws;

    float* mean = ws;                       // 65536
    float* rstd = mean + NPIX;              // 65536
    float* s    = rstd + NPIX;              // 1536
    float* kmax = s + OC3;                  // 8192
    float* ksc  = kmax + 8192;              // 8192
    float* ct   = ksc + 8192;               // 524288
    float* ctp  = ct + 524288;              // 2097152
    h16*  wg_hi = (h16*)(ctp + 2097152);    // 786432 halfs
    h16*  wg_lo = wg_hi + 786432;
    h16*  wo_hi = wg_lo + 786432;           // 262144 halfs
    h16*  wo_lo = wo_hi + 262144;
    float* qkv  = (float*)(wo_lo + 262144); // 100663296 floats
    // aliases of the qkv region (qkv dead after attn_out):
    h16*  at_hi = (h16*)qkv;                // 33554432 halfs
    h16*  at_lo = at_hi + 33554432;
    float* y    = qkv + 33554432;           // 33554432 floats
    // aliases of d_out (xt dead after gemm_qkv; aout dead after 2nd transpose):
    h16*  xt_hi = (h16*)d_out;
    h16*  xt_lo = xt_hi + 33554432;
    float* aout = (float*)d_out;

    const size_t need = 104482304ULL * 4ULL;
    if (ws_size < need) return;

    prep_wg      <<<OC3, 64, 0, stream>>>(w_qkv, g_ln, wg_hi, wg_lo, s);
    prep_wo      <<<CCH, 64, 0, stream>>>(w_out, wo_hi, wo_lo);
    ln_stats     <<<NPIX / 256, 256, 0, stream>>>(x, mean, rstd);
    transpose_cvt<<<dim3(64, 8, 16), 256, 0, stream>>>(x, xt_hi, xt_lo);
    gemm128<OC3, true><<<dim3(512, 12), 256, 0, stream>>>(wg_hi, wg_lo, xt_hi, xt_lo,
                                                          s, mean, rstd, qkv);
    k_stats      <<<256, 256, 0, stream>>>(qkv, kmax, ksc);
    ctx_partial  <<<dim3(4, 128), 256, 0, stream>>>(qkv, kmax, ksc, ctp);
    ctx_reduce   <<<128, 256, 0, stream>>>(ctp, ct);
    attn_out     <<<dim3(8, 128), 256, 0, stream>>>(qkv, ct, aout);
    transpose_cvt<<<dim3(64, 8, 16), 256, 0, stream>>>(aout, at_hi, at_lo);
    gemm128<CCH, false><<<dim3(512, 4), 256, 0, stream>>>(wo_hi, wo_lo, at_hi, at_lo,
                                                          b_out, mean, rstd, y);
    final_ln     <<<256, 256, 0, stream>>>(y, x, g_out, out);
}

// Round 4
// 806.600 us; speedup vs baseline: 2.2894x; 1.1856x over previous
//
#include <hip/hip_runtime.h>
#include <math.h>

#define CCH    512
#define HWN    4096
#define NPIX   65536
#define OC3    1536
#define QSCALE 0.125f
#define LN_EPS 1e-5f

typedef _Float16 h16;
typedef h16  f16x8 __attribute__((ext_vector_type(8)));
typedef float f32x4 __attribute__((ext_vector_type(4)));

__device__ __forceinline__ float waveReduceSum(float v) {
#pragma unroll
    for (int off = 32; off; off >>= 1) v += __shfl_xor(v, off);
    return v;
}
__device__ __forceinline__ float waveReduceMax(float v) {
#pragma unroll
    for (int off = 32; off; off >>= 1) v = fmaxf(v, __shfl_xor(v, off));
    return v;
}

__device__ __forceinline__ void gl_lds16(const void* g, void* l) {
    __builtin_amdgcn_global_load_lds((const __attribute__((address_space(1))) void*)g,
                                     (__attribute__((address_space(3))) void*)l, 16, 0, 0);
}

// ---------------------------------------------------------------------------
// wg = 64 * w_qkv[o,c]*g_ln[c] -> fp16 hi/lo (x64 keeps lo out of fp16 denormals);
// s[o] = sum_c w_qkv[o,c]*g_ln[c]  (unscaled)
__global__ __launch_bounds__(64) void prep_wg(const float* __restrict__ w_qkv,
                                              const float* __restrict__ g_ln,
                                              h16* __restrict__ wh, h16* __restrict__ wl,
                                              float* __restrict__ s) {
    const int o = blockIdx.x, lane = threadIdx.x;
    float sum = 0.f;
#pragma unroll
    for (int j = 0; j < 8; ++j) {
        const int c = lane + j * 64;
        const float w = w_qkv[(size_t)o * CCH + c] * g_ln[c];
        const float ws = w * 64.f;
        const h16 hi = (h16)ws;
        wh[(size_t)o * CCH + c] = hi;
        wl[(size_t)o * CCH + c] = (h16)(ws - (float)hi);
        sum += w;
    }
    sum = waveReduceSum(sum);
    if (lane == 0) s[o] = sum;
}

__global__ __launch_bounds__(64) void prep_wo(const float* __restrict__ w_out,
                                              h16* __restrict__ wh, h16* __restrict__ wl) {
    const int o = blockIdx.x, lane = threadIdx.x;
#pragma unroll
    for (int j = 0; j < 8; ++j) {
        const int c = lane + j * 64;
        const float ws = w_out[(size_t)o * CCH + c] * 64.f;
        const h16 hi = (h16)ws;
        wh[(size_t)o * CCH + c] = hi;
        wl[(size_t)o * CCH + c] = (h16)(ws - (float)hi);
    }
}

// ---------------------------------------------------------------------------
// fp32 [16][512][4096] -> transposed fp16 hi/lo [16][4096][512]
// + per-(channel-block, pixel) LN partial sums (deterministic 2-stage stats)
__global__ __launch_bounds__(256) void transpose_cvt(const float* __restrict__ src,
                                                     h16* __restrict__ dhi,
                                                     h16* __restrict__ dlo,
                                                     float* __restrict__ psum,
                                                     float* __restrict__ psq) {
    __shared__ float tile[64][65];
    __shared__ float ps1[4][64], ps2[4][64];
    const int b = blockIdx.z, c0 = blockIdx.y * 64, p0 = blockIdx.x * 64;
    const int t = threadIdx.x;
    const float* sb = src + ((size_t)b * CCH + c0) * HWN + p0;
    const int rc = t >> 4, cc4 = (t & 15) * 4;
#pragma unroll
    for (int ps = 0; ps < 4; ++ps) {
        const float4 v = *(const float4*)(sb + (size_t)(rc + ps * 16) * HWN + cc4);
        tile[rc + ps * 16][cc4 + 0] = v.x;
        tile[rc + ps * 16][cc4 + 1] = v.y;
        tile[rc + ps * 16][cc4 + 2] = v.z;
        tile[rc + ps * 16][cc4 + 3] = v.w;
    }
    __syncthreads();
    {   // LN partials: wave q sums channels [q*16, q*16+16) for pixel = lane
        const int q = t >> 6, px = t & 63;
        float s1 = 0.f, s2 = 0.f;
#pragma unroll
        for (int c = q * 16; c < q * 16 + 16; ++c) {
            const float v = tile[c][px];
            s1 += v; s2 += v * v;
        }
        ps1[q][px] = s1; ps2[q][px] = s2;
    }
    const int pr0 = t >> 3, cs = (t & 7) * 8;
#pragma unroll
    for (int ps = 0; ps < 2; ++ps) {
        const int pr = pr0 + ps * 32;
        f16x8 vh, vl;
#pragma unroll
        for (int q = 0; q < 8; ++q) {
            const float v = tile[cs + q][pr];
            const h16 hi = (h16)v;
            vh[q] = hi;
            vl[q] = (h16)(v - (float)hi);
        }
        const size_t o = ((size_t)b * HWN + p0 + pr) * CCH + c0 + cs;
        *(f16x8*)(dhi + o) = vh;
        *(f16x8*)(dlo + o) = vl;
    }
    __syncthreads();
    if (t < 64) {
        const float s1 = ps1[0][t] + ps1[1][t] + ps1[2][t] + ps1[3][t];
        const float s2 = ps2[0][t] + ps2[1][t] + ps2[2][t] + ps2[3][t];
        const size_t gp = (size_t)b * HWN + p0 + t;
        psum[(size_t)(c0 >> 6) * NPIX + gp] = s1;
        psq [(size_t)(c0 >> 6) * NPIX + gp] = s2;
    }
}

__global__ __launch_bounds__(256) void ln_finish(const float* __restrict__ psum,
                                                 const float* __restrict__ psq,
                                                 float* __restrict__ mean,
                                                 float* __restrict__ rstd) {
    const int p = blockIdx.x * 256 + threadIdx.x;
    float s1 = 0.f, s2 = 0.f;
#pragma unroll
    for (int cb = 0; cb < 8; ++cb) {
        s1 += psum[(size_t)cb * NPIX + p];
        s2 += psq [(size_t)cb * NPIX + p];
    }
    const float m = s1 * (1.f / 512.f);
    float var = s2 * (1.f / 512.f) - m * m;
    var = fmaxf(var, 0.f);
    mean[p] = m;
    rstd[p] = rsqrtf(var + LN_EPS);
}

// ---------------------------------------------------------------------------
// 128x128 MFMA GEMM, fp16 split-3, K=512. A scaled x64.
// QKV: out fp16 = rstd[p]*(acc/64 - mean[p]*s[o]).
// OUT: out fp32 = acc*2^-27 + bias[o]   (unwinds 64 * 512 * 4096).
template <int OCT, bool QKV>
__global__ __launch_bounds__(256) void gemm128(const h16* __restrict__ Ahg,
                                               const h16* __restrict__ Alg,
                                               const h16* __restrict__ Bhg,
                                               const h16* __restrict__ Blg,
                                               const float* __restrict__ sv,
                                               const float* __restrict__ mean,
                                               const float* __restrict__ rstd,
                                               void* __restrict__ outp) {
    __shared__ __align__(16) h16 Ah[4096], Al[4096], Bh[4096], Bl[4096];
    const int tid = threadIdx.x;
    const int om = blockIdx.y * 128;
    // XCD-chunked swizzle: 512 x-blocks, 8 XCDs, 64 contiguous per XCD (bijective)
    const int bx0 = blockIdx.x;
    const int bx  = (bx0 & 7) * 64 + (bx0 >> 3);
    const int p0  = bx * 128;

    const int srow = tid >> 2;
    const int skh  = ((tid & 3) ^ (srow & 3)) * 8;
    const size_t a0 = (size_t)(om + srow) * CCH + skh;
    const size_t b0 = (size_t)(p0 + srow) * CCH + skh;
    const int wofs = (tid >> 6) * 512;

    const int lane = tid & 63;
    const int wv = tid >> 6;
    const int wm = (wv >> 1) * 64, wn = (wv & 1) * 64;
    const int lr = lane & 15, kg = lane >> 4;
    const int swz = (kg ^ (lr & 3)) * 8;

    f32x4 acc[4][4];
#pragma unroll
    for (int i = 0; i < 4; ++i)
#pragma unroll
        for (int j = 0; j < 4; ++j) acc[i][j] = {0.f, 0.f, 0.f, 0.f};

#define STAGE(KC)                                               \
    do {                                                        \
        gl_lds16(Ahg + a0 + (KC), Ah + wofs);                   \
        gl_lds16(Ahg + a0 + (KC) + 64 * CCH, Ah + 2048 + wofs); \
        gl_lds16(Alg + a0 + (KC), Al + wofs);                   \
        gl_lds16(Alg + a0 + (KC) + 64 * CCH, Al + 2048 + wofs); \
        gl_lds16(Bhg + b0 + (KC), Bh + wofs);                   \
        gl_lds16(Bhg + b0 + (KC) + 64 * CCH, Bh + 2048 + wofs); \
        gl_lds16(Blg + b0 + (KC), Bl + wofs);                   \
        gl_lds16(Blg + b0 + (KC) + 64 * CCH, Bl + 2048 + wofs); \
    } while (0)

    STAGE(0);
#pragma unroll 1
    for (int kc = 0; kc < 512; kc += 32) {
        __syncthreads();
        f16x8 ah[4], al[4], bh[4], bl[4];
#pragma unroll
        for (int i = 0; i < 4; ++i) {
            const int ra = (wm + i * 16 + lr) * 32 + swz;
            ah[i] = *(const f16x8*)(Ah + ra);
            al[i] = *(const f16x8*)(Al + ra);
            const int rb = (wn + i * 16 + lr) * 32 + swz;
            bh[i] = *(const f16x8*)(Bh + rb);
            bl[i] = *(const f16x8*)(Bl + rb);
        }
        __syncthreads();
        if (kc + 32 < 512) STAGE(kc + 32);
#pragma unroll
        for (int i = 0; i < 4; ++i)
#pragma unroll
            for (int j = 0; j < 4; ++j) {
                acc[i][j] = __builtin_amdgcn_mfma_f32_16x16x32_f16(ah[i], bh[j], acc[i][j], 0, 0, 0);
                acc[i][j] = __builtin_amdgcn_mfma_f32_16x16x32_f16(ah[i], bl[j], acc[i][j], 0, 0, 0);
                acc[i][j] = __builtin_amdgcn_mfma_f32_16x16x32_f16(al[i], bh[j], acc[i][j], 0, 0, 0);
            }
    }
#undef STAGE

    // C/D layout: col = lane&15 (n), row = (lane>>4)*4 + reg (m)
    const int b = p0 >> 12, hw0 = p0 & 4095;
    if constexpr (QKV) {
        h16* qout = (h16*)outp;
        float mn[4], rs[4];
#pragma unroll
        for (int j = 0; j < 4; ++j) {
            const int p = p0 + wn + j * 16 + lr;
            mn[j] = mean[p]; rs[j] = rstd[p];
        }
#pragma unroll
        for (int i = 0; i < 4; ++i)
#pragma unroll
            for (int r = 0; r < 4; ++r) {
                const int o = om + wm + i * 16 + kg * 4 + r;
                const float so = sv[o];
                h16* dst = qout + ((size_t)b * OCT + o) * HWN;
#pragma unroll
                for (int j = 0; j < 4; ++j) {
                    const int hw = hw0 + wn + j * 16 + lr;
                    dst[hw] = (h16)(rs[j] * (acc[i][j][r] * (1.f / 64.f) - mn[j] * so));
                }
            }
    } else {
        float* yout = (float*)outp;
#pragma unroll
        for (int i = 0; i < 4; ++i)
#pragma unroll
            for (int r = 0; r < 4; ++r) {
                const int o = om + wm + i * 16 + kg * 4 + r;
                const float bias = sv[o];
                float* dst = yout + ((size_t)b * OCT + o) * HWN;
#pragma unroll
                for (int j = 0; j < 4; ++j) {
                    const int hw = hw0 + wn + j * 16 + lr;
                    dst[hw] = acc[i][j][r] * (1.f / 134217728.f) + bias;
                }
            }
    }
}

// ---------------------------------------------------------------------------
// per-row (over n=4096) max and 1/sum(exp) for k (fp16 input, one wave/row)
__global__ __launch_bounds__(256) void k_stats(const h16* __restrict__ qkv16,
                                               float* __restrict__ kmax,
                                               float* __restrict__ ksc) {
    const int row = blockIdx.x * 4 + (threadIdx.x >> 6);   // 0..8191
    const int bh = row >> 6, r = row & 63;
    const int b = bh >> 3, h = bh & 7;
    const h16* rp = qkv16 + ((size_t)b * OC3 + CCH + h * 64 + r) * HWN;
    const int lane = threadIdx.x & 63;
    f16x8 kv[8];
#pragma unroll
    for (int j = 0; j < 8; ++j) kv[j] = *(const f16x8*)(rp + lane * 8 + j * 512);
    float mx = -1e30f;
#pragma unroll
    for (int j = 0; j < 8; ++j)
#pragma unroll
        for (int u = 0; u < 8; ++u) mx = fmaxf(mx, (float)kv[j][u]);
    mx = waveReduceMax(mx);
    float sum = 0.f;
#pragma unroll
    for (int j = 0; j < 8; ++j)
#pragma unroll
        for (int u = 0; u < 8; ++u) sum += __expf((float)kv[j][u] - mx);
    sum = waveReduceSum(sum);
    if (lane == 0) {
        kmax[row] = mx;
        ksc[row]  = 1.0f / sum;
    }
}

// ---------------------------------------------------------------------------
// partial context over an n-chunk of 1024: ctp = sum_n ktilde[d,n]*V[e,n]
// (V unscaled: the 1/4096 is folded into the out-GEMM epilogue)
__global__ __launch_bounds__(256) void ctx_partial(const h16* __restrict__ qkv16,
                                                   const float* __restrict__ kmax,
                                                   const float* __restrict__ ksc,
                                                   float* __restrict__ ctp) {
    __shared__ float kt[64][68];
    __shared__ float vt[64][68];
    __shared__ float kmx[64], kss[64];

    const int bh = blockIdx.y, ci = blockIdx.x;
    const int b = bh >> 3, h = bh & 7;
    const h16* kb = qkv16 + ((size_t)b * OC3 + CCH  + h * 64) * HWN;
    const h16* vb = qkv16 + ((size_t)b * OC3 + 1024 + h * 64) * HWN;
    const int tid = threadIdx.x;
    if (tid < 64) { kmx[tid] = kmax[bh * 64 + tid]; kss[tid] = ksc[bh * 64 + tid]; }

    const int d  = tid >> 2;
    const int td = tid & 15, te = tid >> 4;
    float acc[4][4];
#pragma unroll
    for (int i = 0; i < 4; ++i)
#pragma unroll
        for (int j = 0; j < 4; ++j) acc[i][j] = 0.f;

    for (int t = 0; t < 16; ++t) {
        const int n0 = ci * 1024 + t * 64;
        __syncthreads();   // guard prev compute & first-iter stats
        const float m = kmx[d], sc = kss[d];
#pragma unroll
        for (int jj = 0; jj < 2; ++jj) {
            const int nn = (tid & 3) * 8 + jj * 32;
            const f16x8 kv = *(const f16x8*)(kb + (size_t)d * HWN + n0 + nn);
            const f16x8 vv = *(const f16x8*)(vb + (size_t)d * HWN + n0 + nn);
#pragma unroll
            for (int u = 0; u < 8; ++u) {
                kt[nn + u][d] = __expf((float)kv[u] - m) * sc;
                vt[nn + u][d] = (float)vv[u];
            }
        }
        __syncthreads();
#pragma unroll
        for (int nn = 0; nn < 64; ++nn) {
            float kf[4], vf[4];
            *(float4*)kf = *(const float4*)&kt[nn][td * 4];
            *(float4*)vf = *(const float4*)&vt[nn][te * 4];
#pragma unroll
            for (int i = 0; i < 4; ++i)
#pragma unroll
                for (int j = 0; j < 4; ++j)
                    acc[i][j] = fmaf(kf[i], vf[j], acc[i][j]);
        }
    }
    float* dst = ctp + ((size_t)bh * 4 + ci) * 4096;
#pragma unroll
    for (int i = 0; i < 4; ++i) {
        const float4 o4 = make_float4(acc[i][0], acc[i][1], acc[i][2], acc[i][3]);
        *(float4*)(dst + (td * 4 + i) * 64 + te * 4) = o4;
    }
}

__global__ __launch_bounds__(256) void ctx_reduce(const float* __restrict__ ctp,
                                                  float* __restrict__ ct) {
    const int bh = blockIdx.x;
    const int tid = threadIdx.x;
    const float* src = ctp + (size_t)bh * 4 * 4096;
    float* dst = ct + (size_t)bh * 4096;
    for (int e4 = tid * 4; e4 < 4096; e4 += 1024) {
        float4 sum = make_float4(0.f, 0.f, 0.f, 0.f);
#pragma unroll
        for (int ci = 0; ci < 4; ++ci) {
            const float4 v = *(const float4*)(src + (size_t)ci * 4096 + e4);
            sum.x += v.x; sum.y += v.y; sum.z += v.z; sum.w += v.w;
        }
        *(float4*)(dst + e4) = sum;
    }
}

// ---------------------------------------------------------------------------
// q-softmax(d) * (512*SCALE), out'[e,n] = sum_d ct[d,e]*qtilde[d,n];
// writes at = split fp16 hi/lo of out', TRANSPOSED to [b*4096+n][512] directly.
__global__ __launch_bounds__(256) void attn_out(const h16* __restrict__ qkv16,
                                                const float* __restrict__ ct,
                                                h16* __restrict__ at_hi,
                                                h16* __restrict__ at_lo) {
    __shared__ float cts[64][68];
    __shared__ float qt[64][68];   // reused as ot[n][e] after compute
    __shared__ float qmx[64], qsc[64];

    const int bh = blockIdx.y, ci = blockIdx.x;
    const int b = bh >> 3, h = bh & 7;
    const h16* qb = qkv16 + ((size_t)b * OC3 + h * 64) * HWN;
    const int tid = threadIdx.x;

    for (int i4 = tid * 4; i4 < 4096; i4 += 1024) {
        const float4 v = *(const float4*)(ct + (size_t)bh * 4096 + i4);
        *(float4*)&cts[i4 >> 6][i4 & 63] = v;
    }

    const int d  = tid >> 2;
    const int te = tid & 15, tn = tid >> 4;

    for (int t = 0; t < 8; ++t) {
        const int n0 = ci * 512 + t * 64;
        __syncthreads();   // cts ready (t=0) / ot fully consumed (t>0)
#pragma unroll
        for (int jj = 0; jj < 2; ++jj) {
            const int nn = (tid & 3) * 8 + jj * 32;
            const f16x8 qv = *(const f16x8*)(qb + (size_t)d * HWN + n0 + nn);
#pragma unroll
            for (int u = 0; u < 8; ++u) qt[nn + u][d] = (float)qv[u];
        }
        __syncthreads();
        if (tid < 64) {
            float mx = -1e30f;
            for (int d2 = 0; d2 < 64; ++d2) {
                const int dd = (d2 + tid) & 63;
                mx = fmaxf(mx, qt[tid][dd]);
            }
            float sm = 0.f;
            for (int d2 = 0; d2 < 64; ++d2) {
                const int dd = (d2 + tid) & 63;
                sm += __expf(qt[tid][dd] - mx);
            }
            qmx[tid] = mx;
            qsc[tid] = 512.f * QSCALE / sm;   // x512 keeps 'at' out of fp16 denormals
        }
        __syncthreads();
        {
            const int nn = tid >> 2;
            const int d0 = (tid & 3) * 16;
            const float m = qmx[nn], sc = qsc[nn];
#pragma unroll
            for (int dd = 0; dd < 16; ++dd)
                qt[nn][d0 + dd] = __expf(qt[nn][d0 + dd] - m) * sc;
        }
        __syncthreads();
        float acc[4][4];
#pragma unroll
        for (int i = 0; i < 4; ++i)
#pragma unroll
            for (int j = 0; j < 4; ++j) acc[i][j] = 0.f;
#pragma unroll
        for (int dd = 0; dd < 64; ++dd) {
            float cv[4];
            *(float4*)cv = *(const float4*)&cts[dd][te * 4];
            const float q0 = qt[tn * 4 + 0][dd];
            const float q1 = qt[tn * 4 + 1][dd];
            const float q2 = qt[tn * 4 + 2][dd];
            const float q3 = qt[tn * 4 + 3][dd];
#pragma unroll
            for (int i = 0; i < 4; ++i) {
                acc[i][0] = fmaf(cv[i], q0, acc[i][0]);
                acc[i][1] = fmaf(cv[i], q1, acc[i][1]);
                acc[i][2] = fmaf(cv[i], q2, acc[i][2]);
                acc[i][3] = fmaf(cv[i], q3, acc[i][3]);
            }
        }
        __syncthreads();   // all reads of qt done; reuse as ot[n][e]
#pragma unroll
        for (int i = 0; i < 4; ++i)
#pragma unroll
            for (int j = 0; j < 4; ++j)
                qt[tn * 4 + j][te * 4 + i] = acc[i][j];
        __syncthreads();
        {   // gather per pixel: 4 threads/pixel, 16 e each; coalesced 128B/pixel
            const int px = tid >> 2, e0 = (tid & 3) * 16;
            f16x8 vh0, vh1, vl0, vl1;
#pragma unroll
            for (int u = 0; u < 8; ++u) {
                const float v0 = qt[px][e0 + u];
                const h16 h0 = (h16)v0;
                vh0[u] = h0; vl0[u] = (h16)(v0 - (float)h0);
                const float v1 = qt[px][e0 + 8 + u];
                const h16 h1 = (h16)v1;
                vh1[u] = h1; vl1[u] = (h16)(v1 - (float)h1);
            }
            const size_t o = ((size_t)b * HWN + n0 + px) * CCH + h * 64 + e0;
            *(f16x8*)(at_hi + o)     = vh0;
            *(f16x8*)(at_hi + o + 8) = vh1;
            *(f16x8*)(at_lo + o)     = vl0;
            *(f16x8*)(at_lo + o + 8) = vl1;
        }
    }
}

// ---------------------------------------------------------------------------
// out = LN_ch(y)*g_out + x   (y already contains bias)
__global__ __launch_bounds__(256) void final_ln(const float* __restrict__ y,
                                                const float* __restrict__ x,
                                                const float* __restrict__ g_out,
                                                float* __restrict__ out) {
    const int p = blockIdx.x * 256 + threadIdx.x;
    const int b = p >> 12, hw = p & 4095;
    const float* yp = y + (size_t)b * CCH * HWN + hw;
    const float* xp = x + (size_t)b * CCH * HWN + hw;
    float* op = out + (size_t)b * CCH * HWN + hw;
    float s1 = 0.f, s2 = 0.f;
#pragma unroll 8
    for (int c = 0; c < CCH; ++c) {
        const float v = yp[(size_t)c * HWN];
        s1 += v; s2 += v * v;
    }
    const float m = s1 * (1.f / 512.f);
    float var = s2 * (1.f / 512.f) - m * m;
    var = fmaxf(var, 0.f);
    const float rs = rsqrtf(var + LN_EPS);
#pragma unroll 8
    for (int c = 0; c < CCH; ++c)
        op[(size_t)c * HWN] = (yp[(size_t)c * HWN] - m) * rs * g_out[c] + xp[(size_t)c * HWN];
}

// ---------------------------------------------------------------------------
extern "C" void kernel_launch(void* const* d_in, const int* in_sizes, int n_in,
                              void* d_out, int out_size, void* d_ws, size_t ws_size,
                              hipStream_t stream) {
    (void)in_sizes; (void)n_in; (void)out_size;
    const float* x     = (const float*)d_in[0];
    const float* w_qkv = (const float*)d_in[1];
    const float* w_out = (const float*)d_in[2];
    const float* b_out = (const float*)d_in[3];
    const float* g_out = (const float*)d_in[4];
    const float* g_ln  = (const float*)d_in[5];
    float* out = (float*)d_out;
    float* ws  = (float*)d_ws;

    float* mean = ws;                       // 65536
    float* rstd = mean + NPIX;              // 65536
    float* s    = rstd + NPIX;              // 1536
    float* kmax = s + OC3;                  // 8192
    float* ksc  = kmax + 8192;              // 8192
    float* ct   = ksc + 8192;               // 524288
    float* ctp  = ct + 524288;              // 2097152 (psum/psq alias: used before ctx)
    float* psum = ctp;                      // 524288
    float* psq  = psum + 524288;            // 524288
    h16*  wg_hi = (h16*)(ctp + 2097152);    // 786432 halfs
    h16*  wg_lo = wg_hi + 786432;
    h16*  wo_hi = wg_lo + 786432;           // 262144 halfs
    h16*  wo_lo = wo_hi + 262144;
    h16*  qkv16 = wo_lo + 262144;           // 100663296 halfs (fp16 q,k,v)
    float* y    = (float*)qkv16;            // 33554432 floats (alias: qkv dead after attn_out)
    // aliases of d_out: xt dead after qkv gemm; at written by attn_out, dead after out gemm
    h16*  xt_hi = (h16*)d_out;
    h16*  xt_lo = xt_hi + 33554432;
    h16*  at_hi = (h16*)d_out;
    h16*  at_lo = at_hi + 33554432;

    const size_t need = 54150656ULL * 4ULL;   // ~216.6 MB
    if (ws_size < need) return;

    prep_wg      <<<OC3, 64, 0, stream>>>(w_qkv, g_ln, wg_hi, wg_lo, s);
    prep_wo      <<<CCH, 64, 0, stream>>>(w_out, wo_hi, wo_lo);
    transpose_cvt<<<dim3(64, 8, 16), 256, 0, stream>>>(x, xt_hi, xt_lo, psum, psq);
    ln_finish    <<<NPIX / 256, 256, 0, stream>>>(psum, psq, mean, rstd);
    gemm128<OC3, true><<<dim3(512, 12), 256, 0, stream>>>(wg_hi, wg_lo, xt_hi, xt_lo,
                                                          s, mean, rstd, qkv16);
    k_stats      <<<2048, 256, 0, stream>>>(qkv16, kmax, ksc);
    ctx_partial  <<<dim3(4, 128), 256, 0, stream>>>(qkv16, kmax, ksc, ctp);
    ctx_reduce   <<<128, 256, 0, stream>>>(ctp, ct);
    attn_out     <<<dim3(8, 128), 256, 0, stream>>>(qkv16, ct, at_hi, at_lo);
    gemm128<CCH, false><<<dim3(512, 4), 256, 0, stream>>>(wo_hi, wo_lo, at_hi, at_lo,
                                                          b_out, mean, rstd, y);
    final_ln     <<<256, 256, 0, stream>>>(y, x, g_out, out);
}

// Round 5
// 766.836 us; speedup vs baseline: 2.4081x; 1.0519x over previous
//
#include <hip/hip_runtime.h>
#include <math.h>

#define CCH    512
#define HWN    4096
#define NPIX   65536
#define OC3    1536
#define QSCALE 0.125f
#define LN_EPS 1e-5f

typedef _Float16 h16;
typedef h16  f16x8 __attribute__((ext_vector_type(8)));
typedef float f32x4 __attribute__((ext_vector_type(4)));

__device__ __forceinline__ float waveReduceSum(float v) {
#pragma unroll
    for (int off = 32; off; off >>= 1) v += __shfl_xor(v, off);
    return v;
}
__device__ __forceinline__ float waveReduceMax(float v) {
#pragma unroll
    for (int off = 32; off; off >>= 1) v = fmaxf(v, __shfl_xor(v, off));
    return v;
}

__device__ __forceinline__ void gl_lds16(const void* g, void* l) {
    __builtin_amdgcn_global_load_lds((const __attribute__((address_space(1))) void*)g,
                                     (__attribute__((address_space(3))) void*)l, 16, 0, 0);
}

// ---------------------------------------------------------------------------
// wg = 64 * w_qkv[o,c]*g_ln[c] -> fp16 hi/lo; s[o] = sum_c w_qkv[o,c]*g_ln[c]
__global__ __launch_bounds__(64) void prep_wg(const float* __restrict__ w_qkv,
                                              const float* __restrict__ g_ln,
                                              h16* __restrict__ wh, h16* __restrict__ wl,
                                              float* __restrict__ s) {
    const int o = blockIdx.x, lane = threadIdx.x;
    float sum = 0.f;
#pragma unroll
    for (int j = 0; j < 8; ++j) {
        const int c = lane + j * 64;
        const float w = w_qkv[(size_t)o * CCH + c] * g_ln[c];
        const float ws = w * 64.f;
        const h16 hi = (h16)ws;
        wh[(size_t)o * CCH + c] = hi;
        wl[(size_t)o * CCH + c] = (h16)(ws - (float)hi);
        sum += w;
    }
    sum = waveReduceSum(sum);
    if (lane == 0) s[o] = sum;
}

__global__ __launch_bounds__(64) void prep_wo(const float* __restrict__ w_out,
                                              h16* __restrict__ wh, h16* __restrict__ wl) {
    const int o = blockIdx.x, lane = threadIdx.x;
#pragma unroll
    for (int j = 0; j < 8; ++j) {
        const int c = lane + j * 64;
        const float ws = w_out[(size_t)o * CCH + c] * 64.f;
        const h16 hi = (h16)ws;
        wh[(size_t)o * CCH + c] = hi;
        wl[(size_t)o * CCH + c] = (h16)(ws - (float)hi);
    }
}

// ---------------------------------------------------------------------------
// fp32 [16][512][4096] -> transposed fp16 hi/lo [16][4096][512]
// + per-(channel-block, pixel) LN partial sums
__global__ __launch_bounds__(256) void transpose_cvt(const float* __restrict__ src,
                                                     h16* __restrict__ dhi,
                                                     h16* __restrict__ dlo,
                                                     float* __restrict__ psum,
                                                     float* __restrict__ psq) {
    __shared__ float tile[64][65];
    __shared__ float ps1[4][64], ps2[4][64];
    const int b = blockIdx.z, c0 = blockIdx.y * 64, p0 = blockIdx.x * 64;
    const int t = threadIdx.x;
    const float* sb = src + ((size_t)b * CCH + c0) * HWN + p0;
    const int rc = t >> 4, cc4 = (t & 15) * 4;
#pragma unroll
    for (int ps = 0; ps < 4; ++ps) {
        const float4 v = *(const float4*)(sb + (size_t)(rc + ps * 16) * HWN + cc4);
        tile[rc + ps * 16][cc4 + 0] = v.x;
        tile[rc + ps * 16][cc4 + 1] = v.y;
        tile[rc + ps * 16][cc4 + 2] = v.z;
        tile[rc + ps * 16][cc4 + 3] = v.w;
    }
    __syncthreads();
    {
        const int q = t >> 6, px = t & 63;
        float s1 = 0.f, s2 = 0.f;
#pragma unroll
        for (int c = q * 16; c < q * 16 + 16; ++c) {
            const float v = tile[c][px];
            s1 += v; s2 += v * v;
        }
        ps1[q][px] = s1; ps2[q][px] = s2;
    }
    const int pr0 = t >> 3, cs = (t & 7) * 8;
#pragma unroll
    for (int ps = 0; ps < 2; ++ps) {
        const int pr = pr0 + ps * 32;
        f16x8 vh, vl;
#pragma unroll
        for (int q = 0; q < 8; ++q) {
            const float v = tile[cs + q][pr];
            const h16 hi = (h16)v;
            vh[q] = hi;
            vl[q] = (h16)(v - (float)hi);
        }
        const size_t o = ((size_t)b * HWN + p0 + pr) * CCH + c0 + cs;
        *(f16x8*)(dhi + o) = vh;
        *(f16x8*)(dlo + o) = vl;
    }
    __syncthreads();
    if (t < 64) {
        const float s1 = ps1[0][t] + ps1[1][t] + ps1[2][t] + ps1[3][t];
        const float s2 = ps2[0][t] + ps2[1][t] + ps2[2][t] + ps2[3][t];
        const size_t gp = (size_t)b * HWN + p0 + t;
        psum[(size_t)(c0 >> 6) * NPIX + gp] = s1;
        psq [(size_t)(c0 >> 6) * NPIX + gp] = s2;
    }
}

__global__ __launch_bounds__(256) void ln_finish(const float* __restrict__ psum,
                                                 const float* __restrict__ psq,
                                                 float* __restrict__ mean,
                                                 float* __restrict__ rstd) {
    const int p = blockIdx.x * 256 + threadIdx.x;
    float s1 = 0.f, s2 = 0.f;
#pragma unroll
    for (int cb = 0; cb < 8; ++cb) {
        s1 += psum[(size_t)cb * NPIX + p];
        s2 += psq [(size_t)cb * NPIX + p];
    }
    const float m = s1 * (1.f / 512.f);
    float var = s2 * (1.f / 512.f) - m * m;
    var = fmaxf(var, 0.f);
    mean[p] = m;
    rstd[p] = rsqrtf(var + LN_EPS);
}

// ---------------------------------------------------------------------------
// QKV GEMM: 128x128 MFMA, fp16 split-3, K=512. A = wg (x64 scaled).
// out fp16 = rstd[p]*(acc/64 - mean[p]*s[o]).
// Grid (12, 512): om fastest-varying so the 12 om-blocks sharing a B panel
// dispatch adjacently (B L2/L3 reuse).
__global__ __launch_bounds__(256) void qkv_gemm(const h16* __restrict__ Ahg,
                                                const h16* __restrict__ Alg,
                                                const h16* __restrict__ Bhg,
                                                const h16* __restrict__ Blg,
                                                const float* __restrict__ sv,
                                                const float* __restrict__ mean,
                                                const float* __restrict__ rstd,
                                                h16* __restrict__ qout) {
    __shared__ __align__(16) h16 Ah[4096], Al[4096], Bh[4096], Bl[4096];
    const int tid = threadIdx.x;
    const int om = blockIdx.x * 128;
    const int by0 = blockIdx.y;
    const int by  = (by0 & 7) * 64 + (by0 >> 3);   // bijective XCD chunking (512%8==0)
    const int p0  = by * 128;

    const int srow = tid >> 2;
    const int skh  = ((tid & 3) ^ (srow & 3)) * 8;
    const size_t a0 = (size_t)(om + srow) * CCH + skh;
    const size_t b0 = (size_t)(p0 + srow) * CCH + skh;
    const int wofs = (tid >> 6) * 512;

    const int lane = tid & 63;
    const int wv = tid >> 6;
    const int wm = (wv >> 1) * 64, wn = (wv & 1) * 64;
    const int lr = lane & 15, kg = lane >> 4;
    const int swz = (kg ^ (lr & 3)) * 8;

    f32x4 acc[4][4];
#pragma unroll
    for (int i = 0; i < 4; ++i)
#pragma unroll
        for (int j = 0; j < 4; ++j) acc[i][j] = {0.f, 0.f, 0.f, 0.f};

#define STAGE(KC)                                               \
    do {                                                        \
        gl_lds16(Ahg + a0 + (KC), Ah + wofs);                   \
        gl_lds16(Ahg + a0 + (KC) + 64 * CCH, Ah + 2048 + wofs); \
        gl_lds16(Alg + a0 + (KC), Al + wofs);                   \
        gl_lds16(Alg + a0 + (KC) + 64 * CCH, Al + 2048 + wofs); \
        gl_lds16(Bhg + b0 + (KC), Bh + wofs);                   \
        gl_lds16(Bhg + b0 + (KC) + 64 * CCH, Bh + 2048 + wofs); \
        gl_lds16(Blg + b0 + (KC), Bl + wofs);                   \
        gl_lds16(Blg + b0 + (KC) + 64 * CCH, Bl + 2048 + wofs); \
    } while (0)

    STAGE(0);
#pragma unroll 1
    for (int kc = 0; kc < 512; kc += 32) {
        __syncthreads();
        f16x8 ah[4], al[4], bh[4], bl[4];
#pragma unroll
        for (int i = 0; i < 4; ++i) {
            const int ra = (wm + i * 16 + lr) * 32 + swz;
            ah[i] = *(const f16x8*)(Ah + ra);
            al[i] = *(const f16x8*)(Al + ra);
            const int rb = (wn + i * 16 + lr) * 32 + swz;
            bh[i] = *(const f16x8*)(Bh + rb);
            bl[i] = *(const f16x8*)(Bl + rb);
        }
        __syncthreads();
        if (kc + 32 < 512) STAGE(kc + 32);
#pragma unroll
        for (int i = 0; i < 4; ++i)
#pragma unroll
            for (int j = 0; j < 4; ++j) {
                acc[i][j] = __builtin_amdgcn_mfma_f32_16x16x32_f16(ah[i], bh[j], acc[i][j], 0, 0, 0);
                acc[i][j] = __builtin_amdgcn_mfma_f32_16x16x32_f16(ah[i], bl[j], acc[i][j], 0, 0, 0);
                acc[i][j] = __builtin_amdgcn_mfma_f32_16x16x32_f16(al[i], bh[j], acc[i][j], 0, 0, 0);
            }
    }
#undef STAGE

    const int b = p0 >> 12, hw0 = p0 & 4095;
    float mn[4], rs[4];
#pragma unroll
    for (int j = 0; j < 4; ++j) {
        const int p = p0 + wn + j * 16 + lr;
        mn[j] = mean[p]; rs[j] = rstd[p];
    }
#pragma unroll
    for (int i = 0; i < 4; ++i)
#pragma unroll
        for (int r = 0; r < 4; ++r) {
            const int o = om + wm + i * 16 + kg * 4 + r;
            const float so = sv[o];
            h16* dst = qout + ((size_t)b * OC3 + o) * HWN;
#pragma unroll
            for (int j = 0; j < 4; ++j) {
                const int hw = hw0 + wn + j * 16 + lr;
                dst[hw] = (h16)(rs[j] * (acc[i][j][r] * (1.f / 64.f) - mn[j] * so));
            }
        }
}

// ---------------------------------------------------------------------------
// per-row (over n=4096) max and 1/sum(exp) for k (fp16 input, one wave/row)
__global__ __launch_bounds__(256) void k_stats(const h16* __restrict__ qkv16,
                                               float* __restrict__ kmax,
                                               float* __restrict__ ksc) {
    const int row = blockIdx.x * 4 + (threadIdx.x >> 6);
    const int bh = row >> 6, r = row & 63;
    const int b = bh >> 3, h = bh & 7;
    const h16* rp = qkv16 + ((size_t)b * OC3 + CCH + h * 64 + r) * HWN;
    const int lane = threadIdx.x & 63;
    f16x8 kv[8];
#pragma unroll
    for (int j = 0; j < 8; ++j) kv[j] = *(const f16x8*)(rp + lane * 8 + j * 512);
    float mx = -1e30f;
#pragma unroll
    for (int j = 0; j < 8; ++j)
#pragma unroll
        for (int u = 0; u < 8; ++u) mx = fmaxf(mx, (float)kv[j][u]);
    mx = waveReduceMax(mx);
    float sum = 0.f;
#pragma unroll
    for (int j = 0; j < 8; ++j)
#pragma unroll
        for (int u = 0; u < 8; ++u) sum += __expf((float)kv[j][u] - mx);
    sum = waveReduceSum(sum);
    if (lane == 0) {
        kmax[row] = mx;
        ksc[row]  = 1.0f / sum;
    }
}

// ---------------------------------------------------------------------------
// partial context over an n-chunk of 1024: ctp = sum_n ktilde[d,n]*V[e,n]
__global__ __launch_bounds__(256) void ctx_partial(const h16* __restrict__ qkv16,
                                                   const float* __restrict__ kmax,
                                                   const float* __restrict__ ksc,
                                                   float* __restrict__ ctp) {
    __shared__ float kt[64][68];
    __shared__ float vt[64][68];
    __shared__ float kmx[64], kss[64];

    const int bh = blockIdx.y, ci = blockIdx.x;
    const int b = bh >> 3, h = bh & 7;
    const h16* kb = qkv16 + ((size_t)b * OC3 + CCH  + h * 64) * HWN;
    const h16* vb = qkv16 + ((size_t)b * OC3 + 1024 + h * 64) * HWN;
    const int tid = threadIdx.x;
    if (tid < 64) { kmx[tid] = kmax[bh * 64 + tid]; kss[tid] = ksc[bh * 64 + tid]; }

    const int d  = tid >> 2;
    const int td = tid & 15, te = tid >> 4;
    float acc[4][4];
#pragma unroll
    for (int i = 0; i < 4; ++i)
#pragma unroll
        for (int j = 0; j < 4; ++j) acc[i][j] = 0.f;

    for (int t = 0; t < 16; ++t) {
        const int n0 = ci * 1024 + t * 64;
        __syncthreads();
        const float m = kmx[d], sc = kss[d];
#pragma unroll
        for (int jj = 0; jj < 2; ++jj) {
            const int nn = (tid & 3) * 8 + jj * 32;
            const f16x8 kv = *(const f16x8*)(kb + (size_t)d * HWN + n0 + nn);
            const f16x8 vv = *(const f16x8*)(vb + (size_t)d * HWN + n0 + nn);
#pragma unroll
            for (int u = 0; u < 8; ++u) {
                kt[nn + u][d] = __expf((float)kv[u] - m) * sc;
                vt[nn + u][d] = (float)vv[u];
            }
        }
        __syncthreads();
#pragma unroll
        for (int nn = 0; nn < 64; ++nn) {
            float kf[4], vf[4];
            *(float4*)kf = *(const float4*)&kt[nn][td * 4];
            *(float4*)vf = *(const float4*)&vt[nn][te * 4];
#pragma unroll
            for (int i = 0; i < 4; ++i)
#pragma unroll
                for (int j = 0; j < 4; ++j)
                    acc[i][j] = fmaf(kf[i], vf[j], acc[i][j]);
        }
    }
    float* dst = ctp + ((size_t)bh * 4 + ci) * 4096;
#pragma unroll
    for (int i = 0; i < 4; ++i) {
        const float4 o4 = make_float4(acc[i][0], acc[i][1], acc[i][2], acc[i][3]);
        *(float4*)(dst + (td * 4 + i) * 64 + te * 4) = o4;
    }
}

__global__ __launch_bounds__(256) void ctx_reduce(const float* __restrict__ ctp,
                                                  float* __restrict__ ct) {
    const int bh = blockIdx.x;
    const int tid = threadIdx.x;
    const float* src = ctp + (size_t)bh * 4 * 4096;
    float* dst = ct + (size_t)bh * 4096;
    for (int e4 = tid * 4; e4 < 4096; e4 += 1024) {
        float4 sum = make_float4(0.f, 0.f, 0.f, 0.f);
#pragma unroll
        for (int ci = 0; ci < 4; ++ci) {
            const float4 v = *(const float4*)(src + (size_t)ci * 4096 + e4);
            sum.x += v.x; sum.y += v.y; sum.z += v.z; sum.w += v.w;
        }
        *(float4*)(dst + e4) = sum;
    }
}

// ---------------------------------------------------------------------------
// q-softmax(d) * (512*SCALE), out'[e,n] = sum_d ct[d,e]*qtilde[d,n];
// writes at = split fp16 hi/lo, TRANSPOSED to [b*4096+n][512] (in ws)
__global__ __launch_bounds__(256) void attn_out(const h16* __restrict__ qkv16,
                                                const float* __restrict__ ct,
                                                h16* __restrict__ at_hi,
                                                h16* __restrict__ at_lo) {
    __shared__ float cts[64][68];
    __shared__ float qt[64][68];
    __shared__ float qmx[64], qsc[64];

    const int bh = blockIdx.y, ci = blockIdx.x;
    const int b = bh >> 3, h = bh & 7;
    const h16* qb = qkv16 + ((size_t)b * OC3 + h * 64) * HWN;
    const int tid = threadIdx.x;

    for (int i4 = tid * 4; i4 < 4096; i4 += 1024) {
        const float4 v = *(const float4*)(ct + (size_t)bh * 4096 + i4);
        *(float4*)&cts[i4 >> 6][i4 & 63] = v;
    }

    const int d  = tid >> 2;
    const int te = tid & 15, tn = tid >> 4;

    for (int t = 0; t < 8; ++t) {
        const int n0 = ci * 512 + t * 64;
        __syncthreads();
#pragma unroll
        for (int jj = 0; jj < 2; ++jj) {
            const int nn = (tid & 3) * 8 + jj * 32;
            const f16x8 qv = *(const f16x8*)(qb + (size_t)d * HWN + n0 + nn);
#pragma unroll
            for (int u = 0; u < 8; ++u) qt[nn + u][d] = (float)qv[u];
        }
        __syncthreads();
        if (tid < 64) {
            float mx = -1e30f;
            for (int d2 = 0; d2 < 64; ++d2) {
                const int dd = (d2 + tid) & 63;
                mx = fmaxf(mx, qt[tid][dd]);
            }
            float sm = 0.f;
            for (int d2 = 0; d2 < 64; ++d2) {
                const int dd = (d2 + tid) & 63;
                sm += __expf(qt[tid][dd] - mx);
            }
            qmx[tid] = mx;
            qsc[tid] = 512.f * QSCALE / sm;
        }
        __syncthreads();
        {
            const int nn = tid >> 2;
            const int d0 = (tid & 3) * 16;
            const float m = qmx[nn], sc = qsc[nn];
#pragma unroll
            for (int dd = 0; dd < 16; ++dd)
                qt[nn][d0 + dd] = __expf(qt[nn][d0 + dd] - m) * sc;
        }
        __syncthreads();
        float acc[4][4];
#pragma unroll
        for (int i = 0; i < 4; ++i)
#pragma unroll
            for (int j = 0; j < 4; ++j) acc[i][j] = 0.f;
#pragma unroll
        for (int dd = 0; dd < 64; ++dd) {
            float cv[4];
            *(float4*)cv = *(const float4*)&cts[dd][te * 4];
            const float q0 = qt[tn * 4 + 0][dd];
            const float q1 = qt[tn * 4 + 1][dd];
            const float q2 = qt[tn * 4 + 2][dd];
            const float q3 = qt[tn * 4 + 3][dd];
#pragma unroll
            for (int i = 0; i < 4; ++i) {
                acc[i][0] = fmaf(cv[i], q0, acc[i][0]);
                acc[i][1] = fmaf(cv[i], q1, acc[i][1]);
                acc[i][2] = fmaf(cv[i], q2, acc[i][2]);
                acc[i][3] = fmaf(cv[i], q3, acc[i][3]);
            }
        }
        __syncthreads();
#pragma unroll
        for (int i = 0; i < 4; ++i)
#pragma unroll
            for (int j = 0; j < 4; ++j)
                qt[tn * 4 + j][te * 4 + i] = acc[i][j];
        __syncthreads();
        {
            const int px = tid >> 2, e0 = (tid & 3) * 16;
            f16x8 vh0, vh1, vl0, vl1;
#pragma unroll
            for (int u = 0; u < 8; ++u) {
                const float v0 = qt[px][e0 + u];
                const h16 h0 = (h16)v0;
                vh0[u] = h0; vl0[u] = (h16)(v0 - (float)h0);
                const float v1 = qt[px][e0 + 8 + u];
                const h16 h1 = (h16)v1;
                vh1[u] = h1; vl1[u] = (h16)(v1 - (float)h1);
            }
            const size_t o = ((size_t)b * HWN + n0 + px) * CCH + h * 64 + e0;
            *(f16x8*)(at_hi + o)     = vh0;
            *(f16x8*)(at_hi + o + 8) = vh1;
            *(f16x8*)(at_lo + o)     = vl0;
            *(f16x8*)(at_lo + o + 8) = vl1;
        }
    }
}

// ---------------------------------------------------------------------------
// Fused out-GEMM + channel LN + residual:
// block = 512 channels x 128 pixels, 8 waves; virtual K = 1536 (split-3 passes:
// (wo_hi,at_hi),(wo_hi,at_lo),(wo_lo,at_hi)); epilogue: y = acc*2^-27 + b_out,
// LN over channels (shfl + LDS cross-wave), out = LN(y)*g_out + x.
__global__ __launch_bounds__(512) void out_fused(const h16* __restrict__ wo_hi,
                                                 const h16* __restrict__ wo_lo,
                                                 const h16* __restrict__ at_hi,
                                                 const h16* __restrict__ at_lo,
                                                 const float* __restrict__ b_out,
                                                 const float* __restrict__ g_out,
                                                 const float* __restrict__ x,
                                                 float* __restrict__ out) {
    __shared__ __align__(16) h16 Alds[512 * 32];   // 32 KB
    __shared__ __align__(16) h16 Blds[128 * 32];   // 8 KB
    __shared__ float red1[4][128], red2[4][128];
    __shared__ float mnS[128], rsS[128];

    const int tid = threadIdx.x;
    const int p0 = blockIdx.x * 128;
    const int b = p0 >> 12, hw0 = p0 & 4095;

    const int trow = tid >> 2;                       // 0..127
    const int skh  = ((tid & 3) ^ (trow & 3)) * 8;   // XOR k-slot swizzle
    const size_t aoff = (size_t)trow * CCH + skh;
    const size_t boff = (size_t)p0 * CCH + aoff;
    const int wofs = (tid >> 6) * 512;

    const int wv = tid >> 6;
    const int wm = (wv >> 1) * 128, wn = (wv & 1) * 64;
    const int lane = tid & 63;
    const int lr = lane & 15, kg = lane >> 4;
    const int swz = (kg ^ (lr & 3)) * 8;

    f32x4 acc[8][4];
#pragma unroll
    for (int i = 0; i < 8; ++i)
#pragma unroll
        for (int j = 0; j < 4; ++j) acc[i][j] = {0.f, 0.f, 0.f, 0.f};

#define STAGEF(S)                                                       \
    do {                                                                \
        const int kc_ = ((S) & 15) * 32;                                \
        const h16* As_ = ((S) < 32) ? wo_hi : wo_lo;                    \
        const h16* Bs_ = (((S) >> 4) == 1) ? at_lo : at_hi;             \
        gl_lds16(As_ + aoff + kc_,               Alds + wofs);          \
        gl_lds16(As_ + aoff + kc_ + 128 * CCH,   Alds + 4096 + wofs);   \
        gl_lds16(As_ + aoff + kc_ + 256 * CCH,   Alds + 8192 + wofs);   \
        gl_lds16(As_ + aoff + kc_ + 384 * CCH,   Alds + 12288 + wofs);  \
        gl_lds16(Bs_ + boff + kc_,               Blds + wofs);          \
    } while (0)

    STAGEF(0);
#pragma unroll 1
    for (int s = 0; s < 48; ++s) {
        __syncthreads();   // staged tile visible
        f16x8 af[8], bf[4];
#pragma unroll
        for (int i = 0; i < 8; ++i)
            af[i] = *(const f16x8*)(Alds + (wm + i * 16 + lr) * 32 + swz);
#pragma unroll
        for (int j = 0; j < 4; ++j)
            bf[j] = *(const f16x8*)(Blds + (wn + j * 16 + lr) * 32 + swz);
        __syncthreads();   // frag reads done; safe to overwrite
        if (s < 47) STAGEF(s + 1);
#pragma unroll
        for (int i = 0; i < 8; ++i)
#pragma unroll
            for (int j = 0; j < 4; ++j)
                acc[i][j] = __builtin_amdgcn_mfma_f32_16x16x32_f16(af[i], bf[j], acc[i][j], 0, 0, 0);
    }
#undef STAGEF

    // ---- epilogue: y = acc*2^-27 + bias ----
#pragma unroll
    for (int i = 0; i < 8; ++i) {
        const int o = wm + i * 16 + kg * 4;
        const float4 bb = *(const float4*)(b_out + o);
#pragma unroll
        for (int j = 0; j < 4; ++j) {
            acc[i][j][0] = acc[i][j][0] * (1.f / 134217728.f) + bb.x;
            acc[i][j][1] = acc[i][j][1] * (1.f / 134217728.f) + bb.y;
            acc[i][j][2] = acc[i][j][2] * (1.f / 134217728.f) + bb.z;
            acc[i][j][3] = acc[i][j][3] * (1.f / 134217728.f) + bb.w;
        }
    }
    // per-pixel LN partials over this wave's 128 channels
    float s1[4], s2[4];
#pragma unroll
    for (int j = 0; j < 4; ++j) {
        s1[j] = 0.f; s2[j] = 0.f;
#pragma unroll
        for (int i = 0; i < 8; ++i)
#pragma unroll
            for (int r = 0; r < 4; ++r) {
                const float v = acc[i][j][r];
                s1[j] += v; s2[j] += v * v;
            }
        s1[j] += __shfl_xor(s1[j], 16); s1[j] += __shfl_xor(s1[j], 32);
        s2[j] += __shfl_xor(s2[j], 16); s2[j] += __shfl_xor(s2[j], 32);
    }
    if (kg == 0) {
#pragma unroll
        for (int j = 0; j < 4; ++j) {
            red1[wv >> 1][wn + j * 16 + lr] = s1[j];
            red2[wv >> 1][wn + j * 16 + lr] = s2[j];
        }
    }
    __syncthreads();
    if (tid < 128) {
        const float S1 = red1[0][tid] + red1[1][tid] + red1[2][tid] + red1[3][tid];
        const float S2 = red2[0][tid] + red2[1][tid] + red2[2][tid] + red2[3][tid];
        const float m = S1 * (1.f / 512.f);
        float var = S2 * (1.f / 512.f) - m * m;
        var = fmaxf(var, 0.f);
        mnS[tid] = m;
        rsS[tid] = rsqrtf(var + LN_EPS);
    }
    __syncthreads();
    float mj[4], rj[4];
#pragma unroll
    for (int j = 0; j < 4; ++j) {
        const int px = wn + j * 16 + lr;
        mj[j] = mnS[px]; rj[j] = rsS[px];
    }
#pragma unroll
    for (int i = 0; i < 8; ++i) {
        const int o = wm + i * 16 + kg * 4;
        const float4 gg = *(const float4*)(g_out + o);
#pragma unroll
        for (int r = 0; r < 4; ++r) {
            const float g = (r == 0) ? gg.x : (r == 1) ? gg.y : (r == 2) ? gg.z : gg.w;
            const float* xr = x + ((size_t)b * CCH + o + r) * HWN + hw0 + wn;
            float* dr = out + ((size_t)b * CCH + o + r) * HWN + hw0 + wn;
#pragma unroll
            for (int j = 0; j < 4; ++j) {
                const int c = j * 16 + lr;
                dr[c] = (acc[i][j][r] - mj[j]) * rj[j] * g + xr[c];
            }
        }
    }
}

// ---------------------------------------------------------------------------
extern "C" void kernel_launch(void* const* d_in, const int* in_sizes, int n_in,
                              void* d_out, int out_size, void* d_ws, size_t ws_size,
                              hipStream_t stream) {
    (void)in_sizes; (void)n_in; (void)out_size;
    const float* x     = (const float*)d_in[0];
    const float* w_qkv = (const float*)d_in[1];
    const float* w_out = (const float*)d_in[2];
    const float* b_out = (const float*)d_in[3];
    const float* g_out = (const float*)d_in[4];
    const float* g_ln  = (const float*)d_in[5];
    float* out = (float*)d_out;
    float* ws  = (float*)d_ws;

    float* mean = ws;                       // 65536
    float* rstd = mean + NPIX;              // 65536
    float* s    = rstd + NPIX;              // 1536
    float* kmax = s + OC3;                  // 8192
    float* ksc  = kmax + 8192;              // 8192
    float* ct   = ksc + 8192;               // 524288
    float* ctp  = ct + 524288;              // 2097152 (psum/psq alias: pre-ctx use)
    float* psum = ctp;                      // 524288
    float* psq  = psum + 524288;            // 524288
    h16*  wg_hi = (h16*)(ctp + 2097152);    // 786432 halfs
    h16*  wg_lo = wg_hi + 786432;
    h16*  wo_hi = wg_lo + 786432;           // 262144 halfs
    h16*  wo_lo = wo_hi + 262144;
    h16*  qkv16 = wo_lo + 262144;           // 100663296 halfs (fp16 q,k,v)
    h16*  at_hi = qkv16 + 100663296;        // 33554432 halfs
    h16*  at_lo = at_hi + 33554432;         // 33554432 halfs
    // aliases of d_out: xt dead after qkv_gemm (out_fused is sole d_out writer)
    h16*  xt_hi = (h16*)d_out;
    h16*  xt_lo = xt_hi + 33554432;

    const size_t need = 87705088ULL * 4ULL;   // ~350.8 MB
    if (ws_size < need) return;

    prep_wg      <<<OC3, 64, 0, stream>>>(w_qkv, g_ln, wg_hi, wg_lo, s);
    prep_wo      <<<CCH, 64, 0, stream>>>(w_out, wo_hi, wo_lo);
    transpose_cvt<<<dim3(64, 8, 16), 256, 0, stream>>>(x, xt_hi, xt_lo, psum, psq);
    ln_finish    <<<NPIX / 256, 256, 0, stream>>>(psum, psq, mean, rstd);
    qkv_gemm     <<<dim3(12, 512), 256, 0, stream>>>(wg_hi, wg_lo, xt_hi, xt_lo,
                                                     s, mean, rstd, qkv16);
    k_stats      <<<2048, 256, 0, stream>>>(qkv16, kmax, ksc);
    ctx_partial  <<<dim3(4, 128), 256, 0, stream>>>(qkv16, kmax, ksc, ctp);
    ctx_reduce   <<<128, 256, 0, stream>>>(ctp, ct);
    attn_out     <<<dim3(8, 128), 256, 0, stream>>>(qkv16, ct, at_hi, at_lo);
    out_fused    <<<512, 512, 0, stream>>>(wo_hi, wo_lo, at_hi, at_lo,
                                           b_out, g_out, x, out);
}

// Round 6
// 587.927 us; speedup vs baseline: 3.1409x; 1.3043x over previous
//
#include <hip/hip_runtime.h>
#include <math.h>

#define CCH    512
#define HWN    4096
#define NPIX   65536
#define OC3    1536
#define QSCALE 0.125f
#define LN_EPS 1e-5f

typedef _Float16 h16;
typedef h16  f16x8 __attribute__((ext_vector_type(8)));
typedef float f32x4 __attribute__((ext_vector_type(4)));

__device__ __forceinline__ float waveReduceSum(float v) {
#pragma unroll
    for (int off = 32; off; off >>= 1) v += __shfl_xor(v, off);
    return v;
}
__device__ __forceinline__ float waveReduceMax(float v) {
#pragma unroll
    for (int off = 32; off; off >>= 1) v = fmaxf(v, __shfl_xor(v, off));
    return v;
}

__device__ __forceinline__ void gl_lds16(const void* g, void* l) {
    __builtin_amdgcn_global_load_lds((const __attribute__((address_space(1))) void*)g,
                                     (__attribute__((address_space(3))) void*)l, 16, 0, 0);
}

// ---------------------------------------------------------------------------
// wg = 64 * w_qkv[o,c]*g_ln[c] -> fp16 hi/lo; s[o] = sum_c w_qkv[o,c]*g_ln[c]
__global__ __launch_bounds__(64) void prep_wg(const float* __restrict__ w_qkv,
                                              const float* __restrict__ g_ln,
                                              h16* __restrict__ wh, h16* __restrict__ wl,
                                              float* __restrict__ s) {
    const int o = blockIdx.x, lane = threadIdx.x;
    float sum = 0.f;
#pragma unroll
    for (int j = 0; j < 8; ++j) {
        const int c = lane + j * 64;
        const float w = w_qkv[(size_t)o * CCH + c] * g_ln[c];
        const float ws = w * 64.f;
        const h16 hi = (h16)ws;
        wh[(size_t)o * CCH + c] = hi;
        wl[(size_t)o * CCH + c] = (h16)(ws - (float)hi);
        sum += w;
    }
    sum = waveReduceSum(sum);
    if (lane == 0) s[o] = sum;
}

__global__ __launch_bounds__(64) void prep_wo(const float* __restrict__ w_out,
                                              h16* __restrict__ wh, h16* __restrict__ wl) {
    const int o = blockIdx.x, lane = threadIdx.x;
#pragma unroll
    for (int j = 0; j < 8; ++j) {
        const int c = lane + j * 64;
        const float ws = w_out[(size_t)o * CCH + c] * 64.f;
        const h16 hi = (h16)ws;
        wh[(size_t)o * CCH + c] = hi;
        wl[(size_t)o * CCH + c] = (h16)(ws - (float)hi);
    }
}

// ---------------------------------------------------------------------------
// fp32 [16][512][4096] -> transposed fp16 [16][4096][512] (single precision half)
// + per-(channel-block, pixel) LN partial sums
__global__ __launch_bounds__(256) void transpose_cvt(const float* __restrict__ src,
                                                     h16* __restrict__ dhi,
                                                     float* __restrict__ psum,
                                                     float* __restrict__ psq) {
    __shared__ float tile[64][65];
    __shared__ float ps1[4][64], ps2[4][64];
    const int b = blockIdx.z, c0 = blockIdx.y * 64, p0 = blockIdx.x * 64;
    const int t = threadIdx.x;
    const float* sb = src + ((size_t)b * CCH + c0) * HWN + p0;
    const int rc = t >> 4, cc4 = (t & 15) * 4;
#pragma unroll
    for (int ps = 0; ps < 4; ++ps) {
        const float4 v = *(const float4*)(sb + (size_t)(rc + ps * 16) * HWN + cc4);
        tile[rc + ps * 16][cc4 + 0] = v.x;
        tile[rc + ps * 16][cc4 + 1] = v.y;
        tile[rc + ps * 16][cc4 + 2] = v.z;
        tile[rc + ps * 16][cc4 + 3] = v.w;
    }
    __syncthreads();
    {
        const int q = t >> 6, px = t & 63;
        float s1 = 0.f, s2 = 0.f;
#pragma unroll
        for (int c = q * 16; c < q * 16 + 16; ++c) {
            const float v = tile[c][px];
            s1 += v; s2 += v * v;
        }
        ps1[q][px] = s1; ps2[q][px] = s2;
    }
    const int pr0 = t >> 3, cs = (t & 7) * 8;
#pragma unroll
    for (int ps = 0; ps < 2; ++ps) {
        const int pr = pr0 + ps * 32;
        f16x8 vh;
#pragma unroll
        for (int q = 0; q < 8; ++q) vh[q] = (h16)tile[cs + q][pr];
        const size_t o = ((size_t)b * HWN + p0 + pr) * CCH + c0 + cs;
        *(f16x8*)(dhi + o) = vh;
    }
    __syncthreads();
    if (t < 64) {
        const float s1 = ps1[0][t] + ps1[1][t] + ps1[2][t] + ps1[3][t];
        const float s2 = ps2[0][t] + ps2[1][t] + ps2[2][t] + ps2[3][t];
        const size_t gp = (size_t)b * HWN + p0 + t;
        psum[(size_t)(c0 >> 6) * NPIX + gp] = s1;
        psq [(size_t)(c0 >> 6) * NPIX + gp] = s2;
    }
}

__global__ __launch_bounds__(256) void ln_finish(const float* __restrict__ psum,
                                                 const float* __restrict__ psq,
                                                 float* __restrict__ mean,
                                                 float* __restrict__ rstd) {
    const int p = blockIdx.x * 256 + threadIdx.x;
    float s1 = 0.f, s2 = 0.f;
#pragma unroll
    for (int cb = 0; cb < 8; ++cb) {
        s1 += psum[(size_t)cb * NPIX + p];
        s2 += psq [(size_t)cb * NPIX + p];
    }
    const float m = s1 * (1.f / 512.f);
    float var = s2 * (1.f / 512.f) - m * m;
    var = fmaxf(var, 0.f);
    mean[p] = m;
    rstd[p] = rsqrtf(var + LN_EPS);
}

// ---------------------------------------------------------------------------
// QKV GEMM: 128x128 MFMA, fp16 split-2 (A hi/lo x B hi), K=512. A = wg (x64).
// out fp16 = rstd[p]*(acc/64 - mean[p]*s[o]).
__global__ __launch_bounds__(256) void qkv_gemm(const h16* __restrict__ Ahg,
                                                const h16* __restrict__ Alg,
                                                const h16* __restrict__ Bhg,
                                                const float* __restrict__ sv,
                                                const float* __restrict__ mean,
                                                const float* __restrict__ rstd,
                                                h16* __restrict__ qout) {
    __shared__ __align__(16) h16 Ah[4096], Al[4096], Bh[4096];
    const int tid = threadIdx.x;
    const int om = blockIdx.x * 128;
    const int by0 = blockIdx.y;
    const int by  = (by0 & 7) * 64 + (by0 >> 3);   // bijective XCD chunking (512%8==0)
    const int p0  = by * 128;

    const int srow = tid >> 2;
    const int skh  = ((tid & 3) ^ (srow & 3)) * 8;
    const size_t a0 = (size_t)(om + srow) * CCH + skh;
    const size_t b0 = (size_t)(p0 + srow) * CCH + skh;
    const int wofs = (tid >> 6) * 512;

    const int lane = tid & 63;
    const int wv = tid >> 6;
    const int wm = (wv >> 1) * 64, wn = (wv & 1) * 64;
    const int lr = lane & 15, kg = lane >> 4;
    const int swz = (kg ^ (lr & 3)) * 8;

    f32x4 acc[4][4];
#pragma unroll
    for (int i = 0; i < 4; ++i)
#pragma unroll
        for (int j = 0; j < 4; ++j) acc[i][j] = {0.f, 0.f, 0.f, 0.f};

#define STAGE(KC)                                               \
    do {                                                        \
        gl_lds16(Ahg + a0 + (KC), Ah + wofs);                   \
        gl_lds16(Ahg + a0 + (KC) + 64 * CCH, Ah + 2048 + wofs); \
        gl_lds16(Alg + a0 + (KC), Al + wofs);                   \
        gl_lds16(Alg + a0 + (KC) + 64 * CCH, Al + 2048 + wofs); \
        gl_lds16(Bhg + b0 + (KC), Bh + wofs);                   \
        gl_lds16(Bhg + b0 + (KC) + 64 * CCH, Bh + 2048 + wofs); \
    } while (0)

    STAGE(0);
#pragma unroll 1
    for (int kc = 0; kc < 512; kc += 32) {
        __syncthreads();
        f16x8 ah[4], al[4], bh[4];
#pragma unroll
        for (int i = 0; i < 4; ++i) {
            const int ra = (wm + i * 16 + lr) * 32 + swz;
            ah[i] = *(const f16x8*)(Ah + ra);
            al[i] = *(const f16x8*)(Al + ra);
            const int rb = (wn + i * 16 + lr) * 32 + swz;
            bh[i] = *(const f16x8*)(Bh + rb);
        }
        __syncthreads();
        if (kc + 32 < 512) STAGE(kc + 32);
#pragma unroll
        for (int i = 0; i < 4; ++i)
#pragma unroll
            for (int j = 0; j < 4; ++j) {
                acc[i][j] = __builtin_amdgcn_mfma_f32_16x16x32_f16(ah[i], bh[j], acc[i][j], 0, 0, 0);
                acc[i][j] = __builtin_amdgcn_mfma_f32_16x16x32_f16(al[i], bh[j], acc[i][j], 0, 0, 0);
            }
    }
#undef STAGE

    const int b = p0 >> 12, hw0 = p0 & 4095;
    float mn[4], rs[4];
#pragma unroll
    for (int j = 0; j < 4; ++j) {
        const int p = p0 + wn + j * 16 + lr;
        mn[j] = mean[p]; rs[j] = rstd[p];
    }
#pragma unroll
    for (int i = 0; i < 4; ++i)
#pragma unroll
        for (int r = 0; r < 4; ++r) {
            const int o = om + wm + i * 16 + kg * 4 + r;
            const float so = sv[o];
            h16* dst = qout + ((size_t)b * OC3 + o) * HWN;
#pragma unroll
            for (int j = 0; j < 4; ++j) {
                const int hw = hw0 + wn + j * 16 + lr;
                dst[hw] = (h16)(rs[j] * (acc[i][j][r] * (1.f / 64.f) - mn[j] * so));
            }
        }
}

// ---------------------------------------------------------------------------
// per-row (over n=4096) max and 1/sum(exp) for k (fp16 input, one wave/row)
__global__ __launch_bounds__(256) void k_stats(const h16* __restrict__ qkv16,
                                               float* __restrict__ kmax,
                                               float* __restrict__ ksc) {
    const int row = blockIdx.x * 4 + (threadIdx.x >> 6);
    const int bh = row >> 6, r = row & 63;
    const int b = bh >> 3, h = bh & 7;
    const h16* rp = qkv16 + ((size_t)b * OC3 + CCH + h * 64 + r) * HWN;
    const int lane = threadIdx.x & 63;
    f16x8 kv[8];
#pragma unroll
    for (int j = 0; j < 8; ++j) kv[j] = *(const f16x8*)(rp + lane * 8 + j * 512);
    float mx = -1e30f;
#pragma unroll
    for (int j = 0; j < 8; ++j)
#pragma unroll
        for (int u = 0; u < 8; ++u) mx = fmaxf(mx, (float)kv[j][u]);
    mx = waveReduceMax(mx);
    float sum = 0.f;
#pragma unroll
    for (int j = 0; j < 8; ++j)
#pragma unroll
        for (int u = 0; u < 8; ++u) sum += __expf((float)kv[j][u] - mx);
    sum = waveReduceSum(sum);
    if (lane == 0) {
        kmax[row] = mx;
        ksc[row]  = 1.0f / sum;
    }
}

// ---------------------------------------------------------------------------
// partial context over an n-chunk of 1024: ctp = sum_n ktilde[d,n]*V[e,n]
__global__ __launch_bounds__(256) void ctx_partial(const h16* __restrict__ qkv16,
                                                   const float* __restrict__ kmax,
                                                   const float* __restrict__ ksc,
                                                   float* __restrict__ ctp) {
    __shared__ float kt[64][68];
    __shared__ float vt[64][68];
    __shared__ float kmx[64], kss[64];

    const int bh = blockIdx.y, ci = blockIdx.x;
    const int b = bh >> 3, h = bh & 7;
    const h16* kb = qkv16 + ((size_t)b * OC3 + CCH  + h * 64) * HWN;
    const h16* vb = qkv16 + ((size_t)b * OC3 + 1024 + h * 64) * HWN;
    const int tid = threadIdx.x;
    if (tid < 64) { kmx[tid] = kmax[bh * 64 + tid]; kss[tid] = ksc[bh * 64 + tid]; }

    const int d  = tid >> 2;
    const int td = tid & 15, te = tid >> 4;
    float acc[4][4];
#pragma unroll
    for (int i = 0; i < 4; ++i)
#pragma unroll
        for (int j = 0; j < 4; ++j) acc[i][j] = 0.f;

    for (int t = 0; t < 16; ++t) {
        const int n0 = ci * 1024 + t * 64;
        __syncthreads();
        const float m = kmx[d], sc = kss[d];
#pragma unroll
        for (int jj = 0; jj < 2; ++jj) {
            const int nn = (tid & 3) * 8 + jj * 32;
            const f16x8 kv = *(const f16x8*)(kb + (size_t)d * HWN + n0 + nn);
            const f16x8 vv = *(const f16x8*)(vb + (size_t)d * HWN + n0 + nn);
#pragma unroll
            for (int u = 0; u < 8; ++u) {
                kt[nn + u][d] = __expf((float)kv[u] - m) * sc;
                vt[nn + u][d] = (float)vv[u];
            }
        }
        __syncthreads();
#pragma unroll
        for (int nn = 0; nn < 64; ++nn) {
            float kf[4], vf[4];
            *(float4*)kf = *(const float4*)&kt[nn][td * 4];
            *(float4*)vf = *(const float4*)&vt[nn][te * 4];
#pragma unroll
            for (int i = 0; i < 4; ++i)
#pragma unroll
                for (int j = 0; j < 4; ++j)
                    acc[i][j] = fmaf(kf[i], vf[j], acc[i][j]);
        }
    }
    float* dst = ctp + ((size_t)bh * 4 + ci) * 4096;
#pragma unroll
    for (int i = 0; i < 4; ++i) {
        const float4 o4 = make_float4(acc[i][0], acc[i][1], acc[i][2], acc[i][3]);
        *(float4*)(dst + (td * 4 + i) * 64 + te * 4) = o4;
    }
}

__global__ __launch_bounds__(256) void ctx_reduce(const float* __restrict__ ctp,
                                                  float* __restrict__ ct) {
    const int bh = blockIdx.x;
    const int tid = threadIdx.x;
    const float* src = ctp + (size_t)bh * 4 * 4096;
    float* dst = ct + (size_t)bh * 4096;
    for (int e4 = tid * 4; e4 < 4096; e4 += 1024) {
        float4 sum = make_float4(0.f, 0.f, 0.f, 0.f);
#pragma unroll
        for (int ci = 0; ci < 4; ++ci) {
            const float4 v = *(const float4*)(src + (size_t)ci * 4096 + e4);
            sum.x += v.x; sum.y += v.y; sum.z += v.z; sum.w += v.w;
        }
        *(float4*)(dst + e4) = sum;
    }
}

// ---------------------------------------------------------------------------
// q-softmax(d) * (512*SCALE), out'[e,n] = sum_d ct[d,e]*qtilde[d,n];
// writes at = fp16 (single), TRANSPOSED to [b*4096+n][512] (in ws).
// Softmax reduce parallelized: 4 lanes per row via shfl (was serial tid<64).
__global__ __launch_bounds__(256) void attn_out(const h16* __restrict__ qkv16,
                                                const float* __restrict__ ct,
                                                h16* __restrict__ at) {
    __shared__ float cts[64][68];
    __shared__ float qt[64][68];

    const int bh = blockIdx.y, ci = blockIdx.x;
    const int b = bh >> 3, h = bh & 7;
    const h16* qb = qkv16 + ((size_t)b * OC3 + h * 64) * HWN;
    const int tid = threadIdx.x;

    for (int i4 = tid * 4; i4 < 4096; i4 += 1024) {
        const float4 v = *(const float4*)(ct + (size_t)bh * 4096 + i4);
        *(float4*)&cts[i4 >> 6][i4 & 63] = v;
    }

    const int d  = tid >> 2;
    const int te = tid & 15, tn = tid >> 4;
    const int rn = tid >> 2, d0q = (tid & 3) * 16;   // softmax: 4 lanes per row

    for (int t = 0; t < 8; ++t) {
        const int n0 = ci * 512 + t * 64;
        __syncthreads();   // cts ready (t=0) / qt fully consumed (t>0)
#pragma unroll
        for (int jj = 0; jj < 2; ++jj) {
            const int nn = (tid & 3) * 8 + jj * 32;
            const f16x8 qv = *(const f16x8*)(qb + (size_t)d * HWN + n0 + nn);
#pragma unroll
            for (int u = 0; u < 8; ++u) qt[nn + u][d] = (float)qv[u];
        }
        __syncthreads();
        {   // wave-parallel softmax over d (row rn, 16 cols per lane)
            float mx = -1e30f;
#pragma unroll
            for (int dd = 0; dd < 16; ++dd) mx = fmaxf(mx, qt[rn][d0q + dd]);
            mx = fmaxf(mx, __shfl_xor(mx, 1));
            mx = fmaxf(mx, __shfl_xor(mx, 2));
            float sm = 0.f;
#pragma unroll
            for (int dd = 0; dd < 16; ++dd) sm += __expf(qt[rn][d0q + dd] - mx);
            sm += __shfl_xor(sm, 1);
            sm += __shfl_xor(sm, 2);
            const float sc = 512.f * QSCALE / sm;   // x512 keeps 'at' well-scaled
#pragma unroll
            for (int dd = 0; dd < 16; ++dd)
                qt[rn][d0q + dd] = __expf(qt[rn][d0q + dd] - mx) * sc;
        }
        __syncthreads();
        float acc[4][4];
#pragma unroll
        for (int i = 0; i < 4; ++i)
#pragma unroll
            for (int j = 0; j < 4; ++j) acc[i][j] = 0.f;
#pragma unroll
        for (int dd = 0; dd < 64; ++dd) {
            float cv[4];
            *(float4*)cv = *(const float4*)&cts[dd][te * 4];
            const float q0 = qt[tn * 4 + 0][dd];
            const float q1 = qt[tn * 4 + 1][dd];
            const float q2 = qt[tn * 4 + 2][dd];
            const float q3 = qt[tn * 4 + 3][dd];
#pragma unroll
            for (int i = 0; i < 4; ++i) {
                acc[i][0] = fmaf(cv[i], q0, acc[i][0]);
                acc[i][1] = fmaf(cv[i], q1, acc[i][1]);
                acc[i][2] = fmaf(cv[i], q2, acc[i][2]);
                acc[i][3] = fmaf(cv[i], q3, acc[i][3]);
            }
        }
        __syncthreads();   // all reads of qt done; reuse as ot[n][e]
#pragma unroll
        for (int i = 0; i < 4; ++i)
#pragma unroll
            for (int j = 0; j < 4; ++j)
                qt[tn * 4 + j][te * 4 + i] = acc[i][j];
        __syncthreads();
        {   // gather per pixel: 4 threads/pixel, 16 e each
            const int px = tid >> 2, e0 = (tid & 3) * 16;
            f16x8 vh0, vh1;
#pragma unroll
            for (int u = 0; u < 8; ++u) {
                vh0[u] = (h16)qt[px][e0 + u];
                vh1[u] = (h16)qt[px][e0 + 8 + u];
            }
            const size_t o = ((size_t)b * HWN + n0 + px) * CCH + h * 64 + e0;
            *(f16x8*)(at + o)     = vh0;
            *(f16x8*)(at + o + 8) = vh1;
        }
    }
}

// ---------------------------------------------------------------------------
// Fused out-GEMM + channel LN + residual. split-2: (wo_hi,at),(wo_lo,at).
// block = 512 channels x 128 pixels, 8 waves; virtual K = 1024 (32 steps).
__global__ __launch_bounds__(512) void out_fused(const h16* __restrict__ wo_hi,
                                                 const h16* __restrict__ wo_lo,
                                                 const h16* __restrict__ at,
                                                 const float* __restrict__ b_out,
                                                 const float* __restrict__ g_out,
                                                 const float* __restrict__ x,
                                                 float* __restrict__ out) {
    __shared__ __align__(16) h16 Alds[512 * 32];   // 32 KB
    __shared__ __align__(16) h16 Blds[128 * 32];   // 8 KB
    __shared__ float red1[4][128], red2[4][128];
    __shared__ float mnS[128], rsS[128];

    const int tid = threadIdx.x;
    const int p0 = blockIdx.x * 128;
    const int b = p0 >> 12, hw0 = p0 & 4095;

    const int trow = tid >> 2;
    const int skh  = ((tid & 3) ^ (trow & 3)) * 8;
    const size_t aoff = (size_t)trow * CCH + skh;
    const size_t boff = (size_t)p0 * CCH + aoff;
    const int wofs = (tid >> 6) * 512;

    const int wv = tid >> 6;
    const int wm = (wv >> 1) * 128, wn = (wv & 1) * 64;
    const int lane = tid & 63;
    const int lr = lane & 15, kg = lane >> 4;
    const int swz = (kg ^ (lr & 3)) * 8;

    f32x4 acc[8][4];
#pragma unroll
    for (int i = 0; i < 8; ++i)
#pragma unroll
        for (int j = 0; j < 4; ++j) acc[i][j] = {0.f, 0.f, 0.f, 0.f};

#define STAGEF(S)                                                       \
    do {                                                                \
        const int kc_ = ((S) & 15) * 32;                                \
        const h16* As_ = ((S) < 16) ? wo_hi : wo_lo;                    \
        gl_lds16(As_ + aoff + kc_,               Alds + wofs);          \
        gl_lds16(As_ + aoff + kc_ + 128 * CCH,   Alds + 4096 + wofs);   \
        gl_lds16(As_ + aoff + kc_ + 256 * CCH,   Alds + 8192 + wofs);   \
        gl_lds16(As_ + aoff + kc_ + 384 * CCH,   Alds + 12288 + wofs);  \
        gl_lds16(at + boff + kc_,                Blds + wofs);          \
    } while (0)

    STAGEF(0);
#pragma unroll 1
    for (int s = 0; s < 32; ++s) {
        __syncthreads();
        f16x8 af[8], bf[4];
#pragma unroll
        for (int i = 0; i < 8; ++i)
            af[i] = *(const f16x8*)(Alds + (wm + i * 16 + lr) * 32 + swz);
#pragma unroll
        for (int j = 0; j < 4; ++j)
            bf[j] = *(const f16x8*)(Blds + (wn + j * 16 + lr) * 32 + swz);
        __syncthreads();
        if (s < 31) STAGEF(s + 1);
#pragma unroll
        for (int i = 0; i < 8; ++i)
#pragma unroll
            for (int j = 0; j < 4; ++j)
                acc[i][j] = __builtin_amdgcn_mfma_f32_16x16x32_f16(af[i], bf[j], acc[i][j], 0, 0, 0);
    }
#undef STAGEF

    // ---- epilogue: y = acc*2^-27 + bias ----
#pragma unroll
    for (int i = 0; i < 8; ++i) {
        const int o = wm + i * 16 + kg * 4;
        const float4 bb = *(const float4*)(b_out + o);
#pragma unroll
        for (int j = 0; j < 4; ++j) {
            acc[i][j][0] = acc[i][j][0] * (1.f / 134217728.f) + bb.x;
            acc[i][j][1] = acc[i][j][1] * (1.f / 134217728.f) + bb.y;
            acc[i][j][2] = acc[i][j][2] * (1.f / 134217728.f) + bb.z;
            acc[i][j][3] = acc[i][j][3] * (1.f / 134217728.f) + bb.w;
        }
    }
    float s1[4], s2[4];
#pragma unroll
    for (int j = 0; j < 4; ++j) {
        s1[j] = 0.f; s2[j] = 0.f;
#pragma unroll
        for (int i = 0; i < 8; ++i)
#pragma unroll
            for (int r = 0; r < 4; ++r) {
                const float v = acc[i][j][r];
                s1[j] += v; s2[j] += v * v;
            }
        s1[j] += __shfl_xor(s1[j], 16); s1[j] += __shfl_xor(s1[j], 32);
        s2[j] += __shfl_xor(s2[j], 16); s2[j] += __shfl_xor(s2[j], 32);
    }
    if (kg == 0) {
#pragma unroll
        for (int j = 0; j < 4; ++j) {
            red1[wv >> 1][wn + j * 16 + lr] = s1[j];
            red2[wv >> 1][wn + j * 16 + lr] = s2[j];
        }
    }
    __syncthreads();
    if (tid < 128) {
        const float S1 = red1[0][tid] + red1[1][tid] + red1[2][tid] + red1[3][tid];
        const float S2 = red2[0][tid] + red2[1][tid] + red2[2][tid] + red2[3][tid];
        const float m = S1 * (1.f / 512.f);
        float var = S2 * (1.f / 512.f) - m * m;
        var = fmaxf(var, 0.f);
        mnS[tid] = m;
        rsS[tid] = rsqrtf(var + LN_EPS);
    }
    __syncthreads();
    float mj[4], rj[4];
#pragma unroll
    for (int j = 0; j < 4; ++j) {
        const int px = wn + j * 16 + lr;
        mj[j] = mnS[px]; rj[j] = rsS[px];
    }
#pragma unroll
    for (int i = 0; i < 8; ++i) {
        const int o = wm + i * 16 + kg * 4;
        const float4 gg = *(const float4*)(g_out + o);
#pragma unroll
        for (int r = 0; r < 4; ++r) {
            const float g = (r == 0) ? gg.x : (r == 1) ? gg.y : (r == 2) ? gg.z : gg.w;
            const float* xr = x + ((size_t)b * CCH + o + r) * HWN + hw0 + wn;
            float* dr = out + ((size_t)b * CCH + o + r) * HWN + hw0 + wn;
#pragma unroll
            for (int j = 0; j < 4; ++j) {
                const int c = j * 16 + lr;
                dr[c] = (acc[i][j][r] - mj[j]) * rj[j] * g + xr[c];
            }
        }
    }
}

// ---------------------------------------------------------------------------
extern "C" void kernel_launch(void* const* d_in, const int* in_sizes, int n_in,
                              void* d_out, int out_size, void* d_ws, size_t ws_size,
                              hipStream_t stream) {
    (void)in_sizes; (void)n_in; (void)out_size;
    const float* x     = (const float*)d_in[0];
    const float* w_qkv = (const float*)d_in[1];
    const float* w_out = (const float*)d_in[2];
    const float* b_out = (const float*)d_in[3];
    const float* g_out = (const float*)d_in[4];
    const float* g_ln  = (const float*)d_in[5];
    float* out = (float*)d_out;
    float* ws  = (float*)d_ws;

    float* mean = ws;                       // 65536
    float* rstd = mean + NPIX;              // 65536
    float* s    = rstd + NPIX;              // 1536
    float* kmax = s + OC3;                  // 8192
    float* ksc  = kmax + 8192;              // 8192
    float* ct   = ksc + 8192;               // 524288
    float* ctp  = ct + 524288;              // 2097152 (psum/psq alias: pre-ctx use)
    float* psum = ctp;                      // 524288
    float* psq  = psum + 524288;            // 524288
    h16*  wg_hi = (h16*)(ctp + 2097152);    // 786432 halfs
    h16*  wg_lo = wg_hi + 786432;
    h16*  wo_hi = wg_lo + 786432;           // 262144 halfs
    h16*  wo_lo = wo_hi + 262144;
    h16*  qkv16 = wo_lo + 262144;           // 100663296 halfs (fp16 q,k,v)
    h16*  at    = qkv16 + 100663296;        // 33554432 halfs (attn out, transposed)
    // alias of d_out: xt dead after qkv_gemm (out_fused is sole d_out writer)
    h16*  xt_hi = (h16*)d_out;

    const size_t need = 70927872ULL * 4ULL;   // ~283.7 MB
    if (ws_size < need) return;

    prep_wg      <<<OC3, 64, 0, stream>>>(w_qkv, g_ln, wg_hi, wg_lo, s);
    prep_wo      <<<CCH, 64, 0, stream>>>(w_out, wo_hi, wo_lo);
    transpose_cvt<<<dim3(64, 8, 16), 256, 0, stream>>>(x, xt_hi, psum, psq);
    ln_finish    <<<NPIX / 256, 256, 0, stream>>>(psum, psq, mean, rstd);
    qkv_gemm     <<<dim3(12, 512), 256, 0, stream>>>(wg_hi, wg_lo, xt_hi,
                                                     s, mean, rstd, qkv16);
    k_stats      <<<2048, 256, 0, stream>>>(qkv16, kmax, ksc);
    ctx_partial  <<<dim3(4, 128), 256, 0, stream>>>(qkv16, kmax, ksc, ctp);
    ctx_reduce   <<<128, 256, 0, stream>>>(ctp, ct);
    attn_out     <<<dim3(8, 128), 256, 0, stream>>>(qkv16, ct, at);
    out_fused    <<<512, 512, 0, stream>>>(wo_hi, wo_lo, at,
                                           b_out, g_out, x, out);
}